// Round 10
// baseline (232.859 us; speedup 1.0000x reference)
//
#include <hip/hip_runtime.h>
#include <hip/hip_bf16.h>

#define D_MODEL 512
#define BATCH 4
#define SEQ 2048
#define ROWS (BATCH*SEQ)   // 8192

typedef unsigned short u16;
typedef short bf16x8 __attribute__((ext_vector_type(8)));
typedef float f32x4 __attribute__((ext_vector_type(4)));

__device__ __forceinline__ float bf2f(u16 u) {
    union { unsigned int i; float f; } v;
    v.i = ((unsigned int)u) << 16;
    return v.f;
}
__device__ __forceinline__ u16 f2bf(float f) {
    union { float f; unsigned int i; } v;
    v.f = f;
    unsigned int x = v.i;
    unsigned int r = (x >> 16) & 1u;
    x += 0x7fffu + r;           // round-to-nearest-even
    return (u16)(x >> 16);
}

template<int N> __device__ __forceinline__ void waitv() {
    static_assert(N==0 || N==3 || N==4, "unsupported vmcnt");
    if constexpr (N == 0) asm volatile("s_waitcnt vmcnt(0)" ::: "memory");
    if constexpr (N == 3) asm volatile("s_waitcnt vmcnt(3)" ::: "memory");
    if constexpr (N == 4) asm volatile("s_waitcnt vmcnt(4)" ::: "memory");
}

// ---------------- fused prep: split x + 4 weights ----------------
__global__ __launch_bounds__(256)
void prep_kernel(const float* __restrict__ x,
                 const float* __restrict__ Wq, const float* __restrict__ Wk,
                 const float* __restrict__ Wv, const float* __restrict__ Wo,
                 u16* __restrict__ xh, u16* __restrict__ xl,
                 u16* __restrict__ whh, u16* __restrict__ whl,
                 u16* __restrict__ woh, u16* __restrict__ wol)
{
    const int blk = blockIdx.x;
    const int tid = threadIdx.x;
    const int WE = 262144;
    const float* src; u16 *dh, *dl; int i;
    if (blk < 4096) {
        src = x; dh = xh; dl = xl;
        i = (blk * 256 + tid) * 4;
    } else {
        int w = (blk - 4096) >> 8;
        src = (w == 0) ? Wq : (w == 1) ? Wk : (w == 2) ? Wv : Wo;
        dh  = (w < 3) ? whh + w * WE : woh;
        dl  = (w < 3) ? whl + w * WE : wol;
        i = (((blk - 4096) & 255) * 256 + tid) * 4;
    }
    float4 v = *(const float4*)(src + i);
    float vv[4] = { v.x, v.y, v.z, v.w };
    u16 hh[4], ll[4];
    #pragma unroll
    for (int j = 0; j < 4; ++j) {
        u16 hi = f2bf(vv[j]);
        hh[j] = hi;
        ll[j] = f2bf(vv[j] - bf2f(hi));
    }
    *(ushort4*)(dh + i) = make_ushort4(hh[0], hh[1], hh[2], hh[3]);
    *(ushort4*)(dl + i) = make_ushort4(ll[0], ll[1], ll[2], ll[3]);
}

// ======== shared GEMM pieces (LDS variants) ========
#define GEMM_PROLOG                                                            \
    constexpr int BN     = 32 * NF;                                            \
    constexpr int TILE_A = 128 * 32;                                           \
    constexpr int TILE_B = BN * 32;                                            \
    constexpr int ACH    = 8;                                                  \
    constexpr int BCH    = BN / 16;                                            \
    constexpr int NCH    = AT*ACH + BT*BCH;                                    \
    constexpr int CPW    = NCH / 4;                                            \
    constexpr int BUFSZ  = AT*TILE_A + BT*TILE_B;                              \
    const int tid  = threadIdx.x;                                              \
    const int lane = tid & 63;                                                 \
    const int wave = tid >> 6;                                                 \
    const int wr = wave >> 1, wc = wave & 1;                                   \
    const int gx = gridDim.x, gy = gridDim.y;                                  \
    int nwg = gx * gy * gridDim.z;                                             \
    int wg  = blockIdx.x + gx * (blockIdx.y + gy * blockIdx.z);                \
    int id  = (wg & 7) * (nwg >> 3) + (wg >> 3);                               \
    const int bx = id % gx;                                                    \
    const int by = (id / gx) % gy;                                             \
    const int bz = id / (gx * gy);                                             \
    const long aBase = (long)bz * aStride + (long)(bx * 128) * lda;            \
    const long bBase = (long)bz * bStride + (long)(by * BN) * ldb;             \
    const u16* csrc[CPW];                                                      \
    unsigned cdst[CPW];                                                        \
    _Pragma("unroll")                                                          \
    for (int i = 0; i < CPW; ++i) {                                            \
        int c = wave + i * 4;                                                  \
        const u16* sb; int ld, lofs, row;                                      \
        if (c < AT * ACH) {                                                    \
            int t = c >> 3;                                                    \
            row = (c & 7) * 16;                                                \
            sb = (t == 0 ? Ah : Al) + aBase;                                   \
            ld = lda; lofs = t * TILE_A;                                       \
        } else {                                                               \
            int cb = c - AT * ACH;                                             \
            int t = cb / BCH;                                                  \
            row = (cb % BCH) * 16;                                             \
            sb = (t == 0 ? Bh : Bl) + bBase;                                   \
            ld = ldb; lofs = AT * TILE_A + t * TILE_B;                         \
        }                                                                      \
        csrc[i] = sb + (long)(row + (lane >> 2)) * ld + (lane & 3) * 8;        \
        cdst[i] = lofs + row * 32;                                             \
    }                                                                          \
    f32x4 acc[4][NF] = {};                                                     \
    const int frow = lane & 15;                                                \
    const int kofs = (lane >> 4) * 8;

#define GEMM_COMPUTE(bb_)                                                      \
    {                                                                          \
        const int bb = (bb_);                                                  \
        bf16x8 aH[4], aL[4], bH[NF], bL[NF];                                   \
        _Pragma("unroll")                                                      \
        for (int m = 0; m < 4; ++m) {                                          \
            int rA = wr*64 + m*16 + frow;                                      \
            aH[m] = *(const bf16x8*)&lds[bb + rA*32 + kofs];                   \
            if constexpr (AT == 2)                                             \
                aL[m] = *(const bf16x8*)&lds[bb + TILE_A + rA*32 + kofs];      \
        }                                                                      \
        _Pragma("unroll")                                                      \
        for (int n = 0; n < NF; ++n) {                                         \
            int rB = wc*(NF*16) + n*16 + frow;                                 \
            bH[n] = *(const bf16x8*)&lds[bb + AT*TILE_A + rB*32 + kofs];       \
            if constexpr (BT == 2)                                             \
                bL[n] = *(const bf16x8*)&lds[bb + AT*TILE_A + TILE_B + rB*32 + kofs]; \
        }                                                                      \
        _Pragma("unroll")                                                      \
        for (int m = 0; m < 4; ++m)                                            \
            _Pragma("unroll")                                                  \
            for (int n = 0; n < NF; ++n) {                                     \
                acc[m][n] = __builtin_amdgcn_mfma_f32_16x16x32_bf16(aH[m], bH[n], acc[m][n], 0, 0, 0); \
                if constexpr (BT == 2)                                         \
                    acc[m][n] = __builtin_amdgcn_mfma_f32_16x16x32_bf16(aH[m], bL[n], acc[m][n], 0, 0, 0); \
                if constexpr (AT == 2)                                         \
                    acc[m][n] = __builtin_amdgcn_mfma_f32_16x16x32_bf16(aL[m], bH[n], acc[m][n], 0, 0, 0); \
            }                                                                  \
    }

#define GEMM_EPILOG                                                            \
    const int rr = (lane >> 4) * 4;                                            \
    _Pragma("unroll")                                                          \
    for (int n = 0; n < NF; ++n) {                                             \
        int colL = by*BN + wc*(NF*16) + n*16 + frow;                           \
        float bv_ = bias ? bias[colL] : 0.0f;                                  \
        _Pragma("unroll")                                                      \
        for (int m = 0; m < 4; ++m) {                                          \
            _Pragma("unroll")                                                  \
            for (int j = 0; j < 4; ++j) {                                      \
                int rowL = bx*128 + wr*64 + m*16 + rr + j;                     \
                float val = acc[m][n][j] * scale + bv_;                        \
                if (mode == 0) {                                               \
                    outF[(long)bz*cStride + (long)rowL*ldc + colL] = val;      \
                } else if (mode == 1) {                                        \
                    long idx = (long)bz*cStride + (long)rowL*ldc + colL;       \
                    u16 h = f2bf(val);                                         \
                    outH[idx] = h;                                             \
                    if (outL) outL[idx] = f2bf(val - bf2f(h));                 \
                } else {                                                       \
                    int b = rowL >> 11;                                        \
                    outH[(long)b*1048576 + (long)colL*2048 + (rowL & 2047)] = f2bf(val); \
                }                                                              \
            }                                                                  \
        }                                                                      \
    }

// ---- 2-buffer variant (round-5 proven; LDS-fat 2,2,2 configs) ----
template<int NF, int AT, int BT>
__global__ __launch_bounds__(256)
void gemm2(const u16* __restrict__ Ah, const u16* __restrict__ Al,
           const u16* __restrict__ Bh, const u16* __restrict__ Bl,
           const float* __restrict__ bias,
           float* __restrict__ outF, u16* __restrict__ outH, u16* __restrict__ outL,
           int K, int lda, int ldb, int ldc,
           long aStride, long bStride, long cStride,
           float scale, int mode)
{
    GEMM_PROLOG
    __shared__ u16 lds[2 * BUFSZ];
    auto stage = [&](int buf, int k0) {
        #pragma unroll
        for (int i = 0; i < CPW; ++i)
            __builtin_amdgcn_global_load_lds(
                (const __attribute__((address_space(1))) unsigned int*)(csrc[i] + k0),
                (__attribute__((address_space(3))) unsigned int*)(&lds[buf * BUFSZ + cdst[i]]),
                16, 0, 0);
    };
    const int nt = K >> 5;
    stage(0, 0);
    __syncthreads();
    int cur = 0;
    for (int t = 0; t < nt; ++t) {
        if (t + 1 < nt) stage(cur ^ 1, (t + 1) << 5);
        GEMM_COMPUTE(cur * BUFSZ)
        __syncthreads();
        cur ^= 1;
    }
    GEMM_EPILOG
}

// ---- ring-3 counted-vmcnt variant (PV) ----
template<int NF, int AT, int BT>
__global__ __launch_bounds__(256)
void gemm3(const u16* __restrict__ Ah, const u16* __restrict__ Al,
           const u16* __restrict__ Bh, const u16* __restrict__ Bl,
           const float* __restrict__ bias,
           float* __restrict__ outF, u16* __restrict__ outH, u16* __restrict__ outL,
           int K, int lda, int ldb, int ldc,
           long aStride, long bStride, long cStride,
           float scale, int mode)
{
    GEMM_PROLOG
    __shared__ u16 lds[3 * BUFSZ];
    auto stage = [&](int buf, int k0) {
        #pragma unroll
        for (int i = 0; i < CPW; ++i)
            __builtin_amdgcn_global_load_lds(
                (const __attribute__((address_space(1))) unsigned int*)(csrc[i] + k0),
                (__attribute__((address_space(3))) unsigned int*)(&lds[buf * BUFSZ + cdst[i]]),
                16, 0, 0);
    };
    const int nt = K >> 5;
    stage(0, 0);
    stage(1, 32);
    for (int t = 0; t < nt; ++t) {
        if (t + 1 < nt) waitv<CPW>();
        else            waitv<0>();
        __builtin_amdgcn_s_barrier();
        __builtin_amdgcn_sched_barrier(0);
        if (t + 2 < nt) stage((t + 2) % 3, (t + 2) << 5);
        GEMM_COMPUTE((t % 3) * BUFSZ)
    }
    GEMM_EPILOG
}

// ---- direct-to-register GEMM: no LDS, no barriers (L2-resident inputs) ----
// C[m,n] = scale * sum_k A[m,k]*B[n,k], bf16 out. BM=128, BN=32*NF, 4 waves.
template<int NF>
__global__ __launch_bounds__(256, 4)
void gemm_reg(const u16* __restrict__ A, const u16* __restrict__ B,
              u16* __restrict__ outH,
              int K, int lda, int ldb, int ldc,
              long aStride, long bStride, long cStride, float scale)
{
    constexpr int BN = 32 * NF;
    const int tid  = threadIdx.x;
    const int lane = tid & 63;
    const int wave = tid >> 6;
    const int wr = wave >> 1, wc = wave & 1;

    // XCD-aware swizzle (grids %8==0)
    const int gx = gridDim.x, gy = gridDim.y;
    int nwg = gx * gy * gridDim.z;
    int wg  = blockIdx.x + gx * (blockIdx.y + gy * blockIdx.z);
    int id  = (wg & 7) * (nwg >> 3) + (wg >> 3);
    const int bx = id % gx;
    const int by = (id / gx) % gy;
    const int bz = id / (gx * gy);

    const int frow = lane & 15;
    const int kofs = (lane >> 4) * 8;

    const u16* aP[4];
    const u16* bP[NF];
    #pragma unroll
    for (int m = 0; m < 4; ++m)
        aP[m] = A + (long)bz*aStride + (long)(bx*128 + wr*64 + m*16 + frow)*lda + kofs;
    #pragma unroll
    for (int n = 0; n < NF; ++n)
        bP[n] = B + (long)bz*bStride + (long)(by*BN + wc*(NF*16) + n*16 + frow)*ldb + kofs;

    f32x4 acc[4][NF] = {};
    const int nt = K >> 5;
    #pragma unroll 2
    for (int t = 0; t < nt; ++t) {
        bf16x8 aH[4], bH[NF];
        #pragma unroll
        for (int m = 0; m < 4; ++m) aH[m] = *(const bf16x8*)(aP[m] + t*32);
        #pragma unroll
        for (int n = 0; n < NF; ++n) bH[n] = *(const bf16x8*)(bP[n] + t*32);
        #pragma unroll
        for (int m = 0; m < 4; ++m)
            #pragma unroll
            for (int n = 0; n < NF; ++n)
                acc[m][n] = __builtin_amdgcn_mfma_f32_16x16x32_bf16(aH[m], bH[n], acc[m][n], 0, 0, 0);
    }

    const int rr = (lane >> 4) * 4;
    #pragma unroll
    for (int n = 0; n < NF; ++n) {
        int colL = by*BN + wc*(NF*16) + n*16 + frow;
        #pragma unroll
        for (int m = 0; m < 4; ++m) {
            #pragma unroll
            for (int j = 0; j < 4; ++j) {
                int rowL = bx*128 + wr*64 + m*16 + rr + j;
                outH[(long)bz*cStride + (long)rowL*ldc + colL] = f2bf(acc[m][n][j] * scale);
            }
        }
    }
}

// ---------------- row softmax over 2048, in-place, bf16 ----------------
__global__ __launch_bounds__(256)
void softmax_kernel(u16* __restrict__ sh)
{
    const long base = (long)blockIdx.x * 2048;
    const int tid = threadIdx.x;
    const int lane = tid & 63, wave = tid >> 6;
    u16* hp = sh + base + tid * 8;
    bf16x8 hv = *(const bf16x8*)hp;
    float s[8];
    #pragma unroll
    for (int j = 0; j < 8; ++j) s[j] = bf2f((u16)hv[j]);

    float mx = s[0];
    #pragma unroll
    for (int j = 1; j < 8; ++j) mx = fmaxf(mx, s[j]);
    #pragma unroll
    for (int off = 32; off >= 1; off >>= 1) mx = fmaxf(mx, __shfl_xor(mx, off));
    __shared__ float red[8];
    if (lane == 0) red[wave] = mx;
    __syncthreads();
    mx = fmaxf(fmaxf(red[0], red[1]), fmaxf(red[2], red[3]));

    float e[8], sum = 0.f;
    #pragma unroll
    for (int j = 0; j < 8; ++j) { e[j] = __expf(s[j] - mx); sum += e[j]; }
    #pragma unroll
    for (int off = 32; off >= 1; off >>= 1) sum += __shfl_xor(sum, off);
    if (lane == 0) red[4 + wave] = sum;
    __syncthreads();
    sum = red[4] + red[5] + red[6] + red[7];
    float inv = 1.0f / sum;

    bf16x8 ho;
    #pragma unroll
    for (int j = 0; j < 8; ++j) ho[j] = (short)f2bf(e[j] * inv);
    *(bf16x8*)hp = ho;
}

extern "C" void kernel_launch(void* const* d_in, const int* in_sizes, int n_in,
                              void* d_out, int out_size, void* d_ws, size_t ws_size,
                              hipStream_t stream)
{
    const float* x  = (const float*)d_in[0];
    const float* Wq = (const float*)d_in[1];
    const float* bq = (const float*)d_in[2];
    const float* Wk = (const float*)d_in[3];
    const float* bk = (const float*)d_in[4];
    const float* Wv = (const float*)d_in[5];
    const float* bv = (const float*)d_in[6];
    const float* Wo = (const float*)d_in[7];
    const float* bo = (const float*)d_in[8];

    char* p = (char*)d_ws;
    auto alloc = [&](size_t bytes) { char* r = p; p += (bytes + 255) & ~(size_t)255; return r; };

    const size_t XE = (size_t)ROWS * D_MODEL;     // 4,194,304
    const size_t WE = (size_t)D_MODEL * D_MODEL;  // 262,144
    const size_t SE = (size_t)BATCH * SEQ * SEQ;  // 16,777,216

    u16* xh   = (u16*)alloc(XE * 2);
    u16* xl   = (u16*)alloc(XE * 2);
    u16* whh  = (u16*)alloc(3 * WE * 2);   // concat Wq,Wk,Wv (hi)
    u16* whl  = (u16*)alloc(3 * WE * 2);   // concat (lo)
    u16* woh  = (u16*)alloc(WE * 2);
    u16* wol  = (u16*)alloc(WE * 2);
    u16* qh   = (u16*)alloc(XE * 2);
    u16* kh   = (u16*)alloc(XE * 2);
    u16* vTh  = (u16*)alloc(XE * 2);
    u16* sh   = (u16*)alloc(SE * 2);
    // att (split) aliases x's split buffers — x dead after V projection
    u16* ath = xh;
    u16* atl = xl;

    // 1. fused prep (1 launch)
    prep_kernel<<<5120, 256, 0, stream>>>(x, Wq, Wk, Wv, Wo,
                                          xh, xl, whh, whl, woh, wol);

    // 2. q/k/v projections: 3-term split, 2-buffer schedule
    gemm2<2,2,2><<<dim3(64, 8, 1), 256, 0, stream>>>(xh, xl, whh, whl, bq,
        nullptr, qh, nullptr, 512, 512, 512, 512, 0, 0, 0, 1.0f, 1);
    gemm2<2,2,2><<<dim3(64, 8, 1), 256, 0, stream>>>(xh, xl, whh + WE, whl + WE, bk,
        nullptr, kh, nullptr, 512, 512, 512, 512, 0, 0, 0, 1.0f, 1);
    gemm2<2,2,2><<<dim3(64, 8, 1), 256, 0, stream>>>(xh, xl, whh + 2*WE, whl + 2*WE, bv,
        nullptr, vTh, nullptr, 512, 512, 512, 512, 0, 0, 0, 1.0f, 2);

    // 3. scores = q@k^T * 1/sqrt(512): direct-to-register, no LDS, no barriers
    gemm_reg<4><<<dim3(16, 16, 4), 256, 0, stream>>>(qh, kh, sh,
        512, 512, 512, 2048,
        (long)SEQ * 512, (long)SEQ * 512, (long)SEQ * SEQ,
        0.044194173824159216f);

    // 4. softmax rows (bf16 in/out)
    softmax_kernel<<<ROWS, 256, 0, stream>>>(sh);

    // 5. att = p @ v: 1-term, ring-3; split output (feeds 3-term final)
    gemm3<2,1,1><<<dim3(16, 8, 4), 256, 0, stream>>>(sh, nullptr, vTh, nullptr, nullptr,
        nullptr, ath, atl, 2048, 2048, 2048, 512,
        (long)SEQ * SEQ, (long)512 * SEQ, (long)SEQ * 512,
        1.0f, 1);

    // 6. out = att @ Wo^T + bo: 3-term, 2-buffer, fp32 out
    gemm2<2,2,2><<<dim3(64, 8, 1), 256, 0, stream>>>(ath, atl, woh, wol, bo,
        (float*)d_out, nullptr, nullptr, 512, 512, 512, 512,
        0, 0, 0, 1.0f, 0);
}

// Round 11
// 218.948 us; speedup vs baseline: 1.0635x; 1.0635x over previous
//
#include <hip/hip_runtime.h>
#include <hip/hip_bf16.h>

#define D_MODEL 512
#define BATCH 4
#define SEQ 2048
#define ROWS (BATCH*SEQ)   // 8192

typedef unsigned short u16;
typedef short bf16x8 __attribute__((ext_vector_type(8)));
typedef float f32x4 __attribute__((ext_vector_type(4)));

__device__ __forceinline__ float bf2f(u16 u) {
    union { unsigned int i; float f; } v;
    v.i = ((unsigned int)u) << 16;
    return v.f;
}
__device__ __forceinline__ u16 f2bf(float f) {
    union { float f; unsigned int i; } v;
    v.f = f;
    unsigned int x = v.i;
    unsigned int r = (x >> 16) & 1u;
    x += 0x7fffu + r;           // round-to-nearest-even
    return (u16)(x >> 16);
}

template<int N> __device__ __forceinline__ void waitv() {
    static_assert(N==0 || N==3 || N==4, "unsupported vmcnt");
    if constexpr (N == 0) asm volatile("s_waitcnt vmcnt(0)" ::: "memory");
    if constexpr (N == 3) asm volatile("s_waitcnt vmcnt(3)" ::: "memory");
    if constexpr (N == 4) asm volatile("s_waitcnt vmcnt(4)" ::: "memory");
}

// ---------------- fused prep: split x + 4 weights ----------------
__global__ __launch_bounds__(256)
void prep_kernel(const float* __restrict__ x,
                 const float* __restrict__ Wq, const float* __restrict__ Wk,
                 const float* __restrict__ Wv, const float* __restrict__ Wo,
                 u16* __restrict__ xh, u16* __restrict__ xl,
                 u16* __restrict__ whh, u16* __restrict__ whl,
                 u16* __restrict__ woh, u16* __restrict__ wol)
{
    const int blk = blockIdx.x;
    const int tid = threadIdx.x;
    const int WE = 262144;
    const float* src; u16 *dh, *dl; int i;
    if (blk < 4096) {
        src = x; dh = xh; dl = xl;
        i = (blk * 256 + tid) * 4;
    } else {
        int w = (blk - 4096) >> 8;
        src = (w == 0) ? Wq : (w == 1) ? Wk : (w == 2) ? Wv : Wo;
        dh  = (w < 3) ? whh + w * WE : woh;
        dl  = (w < 3) ? whl + w * WE : wol;
        i = (((blk - 4096) & 255) * 256 + tid) * 4;
    }
    float4 v = *(const float4*)(src + i);
    float vv[4] = { v.x, v.y, v.z, v.w };
    u16 hh[4], ll[4];
    #pragma unroll
    for (int j = 0; j < 4; ++j) {
        u16 hi = f2bf(vv[j]);
        hh[j] = hi;
        ll[j] = f2bf(vv[j] - bf2f(hi));
    }
    *(ushort4*)(dh + i) = make_ushort4(hh[0], hh[1], hh[2], hh[3]);
    *(ushort4*)(dl + i) = make_ushort4(ll[0], ll[1], ll[2], ll[3]);
}

// ======== shared GEMM pieces ========
#define GEMM_PROLOG                                                            \
    constexpr int BN     = 32 * NF;                                            \
    constexpr int TILE_A = 128 * 32;                                           \
    constexpr int TILE_B = BN * 32;                                            \
    constexpr int ACH    = 8;                                                  \
    constexpr int BCH    = BN / 16;                                            \
    constexpr int NCH    = AT*ACH + BT*BCH;                                    \
    constexpr int CPW    = NCH / 4;                                            \
    constexpr int BUFSZ  = AT*TILE_A + BT*TILE_B;                              \
    const int tid  = threadIdx.x;                                              \
    const int lane = tid & 63;                                                 \
    const int wave = tid >> 6;                                                 \
    const int wr = wave >> 1, wc = wave & 1;                                   \
    const int gx = gridDim.x, gy = gridDim.y;                                  \
    int nwg = gx * gy * gridDim.z;                                             \
    int wg  = blockIdx.x + gx * (blockIdx.y + gy * blockIdx.z);                \
    int id  = (wg & 7) * (nwg >> 3) + (wg >> 3);                               \
    const int bx = id % gx;                                                    \
    const int by = (id / gx) % gy;                                             \
    const int bz = id / (gx * gy);                                             \
    const long aBase = (long)bz * aStride + (long)(bx * 128) * lda;            \
    const long bBase = (long)bz * bStride + (long)(by * BN) * ldb;             \
    const u16* csrc[CPW];                                                      \
    unsigned cdst[CPW];                                                        \
    _Pragma("unroll")                                                          \
    for (int i = 0; i < CPW; ++i) {                                            \
        int c = wave + i * 4;                                                  \
        const u16* sb; int ld, lofs, row;                                      \
        if (c < AT * ACH) {                                                    \
            int t = c >> 3;                                                    \
            row = (c & 7) * 16;                                                \
            sb = (t == 0 ? Ah : Al) + aBase;                                   \
            ld = lda; lofs = t * TILE_A;                                       \
        } else {                                                               \
            int cb = c - AT * ACH;                                             \
            int t = cb / BCH;                                                  \
            row = (cb % BCH) * 16;                                             \
            sb = (t == 0 ? Bh : Bl) + bBase;                                   \
            ld = ldb; lofs = AT * TILE_A + t * TILE_B;                         \
        }                                                                      \
        csrc[i] = sb + (long)(row + (lane >> 2)) * ld + (lane & 3) * 8;        \
        cdst[i] = lofs + row * 32;                                             \
    }                                                                          \
    f32x4 acc[4][NF] = {};                                                     \
    const int frow = lane & 15;                                                \
    const int kofs = (lane >> 4) * 8;

#define GEMM_COMPUTE(bb_)                                                      \
    {                                                                          \
        const int bb = (bb_);                                                  \
        bf16x8 aH[4], aL[4], bH[NF], bL[NF];                                   \
        _Pragma("unroll")                                                      \
        for (int m = 0; m < 4; ++m) {                                          \
            int rA = wr*64 + m*16 + frow;                                      \
            aH[m] = *(const bf16x8*)&lds[bb + rA*32 + kofs];                   \
            if constexpr (AT == 2)                                             \
                aL[m] = *(const bf16x8*)&lds[bb + TILE_A + rA*32 + kofs];      \
        }                                                                      \
        _Pragma("unroll")                                                      \
        for (int n = 0; n < NF; ++n) {                                         \
            int rB = wc*(NF*16) + n*16 + frow;                                 \
            bH[n] = *(const bf16x8*)&lds[bb + AT*TILE_A + rB*32 + kofs];       \
            if constexpr (BT == 2)                                             \
                bL[n] = *(const bf16x8*)&lds[bb + AT*TILE_A + TILE_B + rB*32 + kofs]; \
        }                                                                      \
        _Pragma("unroll")                                                      \
        for (int m = 0; m < 4; ++m)                                            \
            _Pragma("unroll")                                                  \
            for (int n = 0; n < NF; ++n) {                                     \
                acc[m][n] = __builtin_amdgcn_mfma_f32_16x16x32_bf16(aH[m], bH[n], acc[m][n], 0, 0, 0); \
                if constexpr (BT == 2)                                         \
                    acc[m][n] = __builtin_amdgcn_mfma_f32_16x16x32_bf16(aH[m], bL[n], acc[m][n], 0, 0, 0); \
                if constexpr (AT == 2)                                         \
                    acc[m][n] = __builtin_amdgcn_mfma_f32_16x16x32_bf16(aL[m], bH[n], acc[m][n], 0, 0, 0); \
            }                                                                  \
    }

// LDS-staged epilogue: write C tile to LDS (padded stride), barrier, then
// fully-coalesced 16B/lane stores (full 64B lines -> no write-allocate RMW).
#define GEMM_EPILOG_STAGED                                                     \
    {                                                                          \
    const int rr = (lane >> 4) * 4;                                            \
    __syncthreads();                                                           \
    if (mode == 0) {                                                           \
        float* ldsF = (float*)lds;                                             \
        _Pragma("unroll")                                                      \
        for (int n = 0; n < NF; ++n) {                                         \
            int c = wc*(NF*16) + n*16 + frow;                                  \
            float bv_ = bias ? bias[by*BN + c] : 0.0f;                         \
            _Pragma("unroll")                                                  \
            for (int m = 0; m < 4; ++m)                                        \
                _Pragma("unroll")                                              \
                for (int j = 0; j < 4; ++j)                                    \
                    ldsF[(wr*64 + m*16 + rr + j)*(BN+4) + c] = acc[m][n][j]*scale + bv_; \
        }                                                                      \
        __syncthreads();                                                       \
        for (int idx = tid; idx < 128*(BN/4); idx += 256) {                    \
            int row = idx / (BN/4), c4 = (idx % (BN/4)) * 4;                   \
            *(float4*)&outF[(long)bz*cStride + (long)(bx*128+row)*ldc + by*BN + c4] = \
                *(float4*)&ldsF[row*(BN+4) + c4];                              \
        }                                                                      \
    } else if (mode == 1) {                                                    \
        u16* ldsH = (u16*)lds;                                                 \
        u16* ldsL = (u16*)lds + 128*(BN+12);                                   \
        _Pragma("unroll")                                                      \
        for (int n = 0; n < NF; ++n) {                                         \
            int c = wc*(NF*16) + n*16 + frow;                                  \
            float bv_ = bias ? bias[by*BN + c] : 0.0f;                         \
            _Pragma("unroll")                                                  \
            for (int m = 0; m < 4; ++m)                                        \
                _Pragma("unroll")                                              \
                for (int j = 0; j < 4; ++j) {                                  \
                    int r = wr*64 + m*16 + rr + j;                             \
                    float val = acc[m][n][j]*scale + bv_;                      \
                    u16 h = f2bf(val);                                         \
                    ldsH[r*(BN+12) + c] = h;                                   \
                    if (outL) ldsL[r*(BN+12) + c] = f2bf(val - bf2f(h));       \
                }                                                              \
        }                                                                      \
        __syncthreads();                                                       \
        for (int idx = tid; idx < 128*(BN/8); idx += 256) {                    \
            int row = idx / (BN/8), c8 = (idx % (BN/8)) * 8;                   \
            long o = (long)bz*cStride + (long)(bx*128+row)*ldc + by*BN + c8;   \
            *(bf16x8*)&outH[o] = *(bf16x8*)&ldsH[row*(BN+12) + c8];            \
            if (outL) *(bf16x8*)&outL[o] = *(bf16x8*)&ldsL[row*(BN+12) + c8];  \
        }                                                                      \
    } else {                                                                   \
        u16* ldsT = (u16*)lds;   /* [BN][136]: transposed tile */              \
        _Pragma("unroll")                                                      \
        for (int n = 0; n < NF; ++n) {                                         \
            int c = wc*(NF*16) + n*16 + frow;                                  \
            float bv_ = bias ? bias[by*BN + c] : 0.0f;                         \
            _Pragma("unroll")                                                  \
            for (int m = 0; m < 4; ++m)                                        \
                _Pragma("unroll")                                              \
                for (int j = 0; j < 4; ++j)                                    \
                    ldsT[c*136 + (wr*64 + m*16 + rr + j)] = f2bf(acc[m][n][j]*scale + bv_); \
        }                                                                      \
        __syncthreads();                                                       \
        int b = bx >> 4, mrowBase = (bx & 15) * 128;                           \
        for (int idx = tid; idx < BN*16; idx += 256) {                         \
            int crow = idx >> 4, r8 = (idx & 15) * 8;                          \
            *(bf16x8*)&outH[(long)b*1048576 + (long)(by*BN + crow)*2048 + mrowBase + r8] = \
                *(bf16x8*)&ldsT[crow*136 + r8];                                \
        }                                                                      \
    }                                                                          \
    }

// ---- 2-buffer variant (projections, final) ----
template<int NF, int AT, int BT>
__global__ __launch_bounds__(256)
void gemm2(const u16* __restrict__ Ah, const u16* __restrict__ Al,
           const u16* __restrict__ Bh, const u16* __restrict__ Bl,
           const float* __restrict__ bias,
           float* __restrict__ outF, u16* __restrict__ outH, u16* __restrict__ outL,
           int K, int lda, int ldb, int ldc,
           long aStride, long bStride, long cStride,
           float scale, int mode)
{
    GEMM_PROLOG
    constexpr int EPI1 = 128*(BN+12);       // mode1 hi tile (u16)
    constexpr int EPI0 = 256*(BN+4);        // mode0 f32 tile in u16 units
    constexpr int LDSN = (2*BUFSZ > EPI1 ? (2*BUFSZ > EPI0 ? 2*BUFSZ : EPI0)
                                         : (EPI1 > EPI0 ? EPI1 : EPI0));
    __shared__ u16 lds[LDSN];
    auto stage = [&](int buf, int k0) {
        #pragma unroll
        for (int i = 0; i < CPW; ++i)
            __builtin_amdgcn_global_load_lds(
                (const __attribute__((address_space(1))) unsigned int*)(csrc[i] + k0),
                (__attribute__((address_space(3))) unsigned int*)(&lds[buf * BUFSZ + cdst[i]]),
                16, 0, 0);
    };
    const int nt = K >> 5;
    stage(0, 0);
    __syncthreads();
    int cur = 0;
    for (int t = 0; t < nt; ++t) {
        if (t + 1 < nt) stage(cur ^ 1, (t + 1) << 5);
        GEMM_COMPUTE(cur * BUFSZ)
        __syncthreads();
        cur ^= 1;
    }
    GEMM_EPILOG_STAGED
}

// ---- ring-3 counted-vmcnt variant (PV) ----
template<int NF, int AT, int BT>
__global__ __launch_bounds__(256)
void gemm3(const u16* __restrict__ Ah, const u16* __restrict__ Al,
           const u16* __restrict__ Bh, const u16* __restrict__ Bl,
           const float* __restrict__ bias,
           float* __restrict__ outF, u16* __restrict__ outH, u16* __restrict__ outL,
           int K, int lda, int ldb, int ldc,
           long aStride, long bStride, long cStride,
           float scale, int mode)
{
    GEMM_PROLOG
    constexpr int EPI1 = 256*(BN+12);       // mode1 hi+lo tiles (u16)
    constexpr int LDSN = (3*BUFSZ > EPI1) ? 3*BUFSZ : EPI1;
    __shared__ u16 lds[LDSN];
    auto stage = [&](int buf, int k0) {
        #pragma unroll
        for (int i = 0; i < CPW; ++i)
            __builtin_amdgcn_global_load_lds(
                (const __attribute__((address_space(1))) unsigned int*)(csrc[i] + k0),
                (__attribute__((address_space(3))) unsigned int*)(&lds[buf * BUFSZ + cdst[i]]),
                16, 0, 0);
    };
    const int nt = K >> 5;
    stage(0, 0);
    stage(1, 32);
    for (int t = 0; t < nt; ++t) {
        if (t + 1 < nt) waitv<CPW>();
        else            waitv<0>();
        __builtin_amdgcn_s_barrier();
        __builtin_amdgcn_sched_barrier(0);
        if (t + 2 < nt) stage((t + 2) % 3, (t + 2) << 5);
        GEMM_COMPUTE((t % 3) * BUFSZ)
    }
    GEMM_EPILOG_STAGED
}

// ---- direct-to-register GEMM (scores): no LDS in K-loop; staged epilogue ----
template<int NF>
__global__ __launch_bounds__(256, 4)
void gemm_reg(const u16* __restrict__ A, const u16* __restrict__ B,
              u16* __restrict__ outH,
              int K, int lda, int ldb, int ldc,
              long aStride, long bStride, long cStride, float scale)
{
    constexpr int BN = 32 * NF;
    __shared__ u16 ldsC[128 * 136];
    const int tid  = threadIdx.x;
    const int lane = tid & 63;
    const int wave = tid >> 6;
    const int wr = wave >> 1, wc = wave & 1;

    const int gx = gridDim.x, gy = gridDim.y;
    int nwg = gx * gy * gridDim.z;
    int wg  = blockIdx.x + gx * (blockIdx.y + gy * blockIdx.z);
    int id  = (wg & 7) * (nwg >> 3) + (wg >> 3);
    const int bx = id % gx;
    const int by = (id / gx) % gy;
    const int bz = id / (gx * gy);

    const int frow = lane & 15;
    const int kofs = (lane >> 4) * 8;

    const u16* aP[4];
    const u16* bP[NF];
    #pragma unroll
    for (int m = 0; m < 4; ++m)
        aP[m] = A + (long)bz*aStride + (long)(bx*128 + wr*64 + m*16 + frow)*lda + kofs;
    #pragma unroll
    for (int n = 0; n < NF; ++n)
        bP[n] = B + (long)bz*bStride + (long)(by*BN + wc*(NF*16) + n*16 + frow)*ldb + kofs;

    f32x4 acc[4][NF] = {};
    const int nt = K >> 5;
    #pragma unroll 2
    for (int t = 0; t < nt; ++t) {
        bf16x8 aH[4], bH[NF];
        #pragma unroll
        for (int m = 0; m < 4; ++m) aH[m] = *(const bf16x8*)(aP[m] + t*32);
        #pragma unroll
        for (int n = 0; n < NF; ++n) bH[n] = *(const bf16x8*)(bP[n] + t*32);
        #pragma unroll
        for (int m = 0; m < 4; ++m)
            #pragma unroll
            for (int n = 0; n < NF; ++n)
                acc[m][n] = __builtin_amdgcn_mfma_f32_16x16x32_bf16(aH[m], bH[n], acc[m][n], 0, 0, 0);
    }

    // staged epilogue: LDS tile [128][136] -> coalesced bf16x8 stores
    const int rr = (lane >> 4) * 4;
    #pragma unroll
    for (int n = 0; n < NF; ++n) {
        int c = wc*(NF*16) + n*16 + frow;
        #pragma unroll
        for (int m = 0; m < 4; ++m)
            #pragma unroll
            for (int j = 0; j < 4; ++j)
                ldsC[(wr*64 + m*16 + rr + j)*136 + c] = f2bf(acc[m][n][j] * scale);
    }
    __syncthreads();
    for (int idx = tid; idx < 128*(BN/8); idx += 256) {
        int row = idx / (BN/8), c8 = (idx % (BN/8)) * 8;
        *(bf16x8*)&outH[(long)bz*cStride + (long)(bx*128+row)*ldc + by*BN + c8] =
            *(bf16x8*)&ldsC[row*136 + c8];
    }
}

// ---------------- row softmax over 2048, in-place, bf16 ----------------
__global__ __launch_bounds__(256)
void softmax_kernel(u16* __restrict__ sh)
{
    const long base = (long)blockIdx.x * 2048;
    const int tid = threadIdx.x;
    const int lane = tid & 63, wave = tid >> 6;
    u16* hp = sh + base + tid * 8;
    bf16x8 hv = *(const bf16x8*)hp;
    float s[8];
    #pragma unroll
    for (int j = 0; j < 8; ++j) s[j] = bf2f((u16)hv[j]);

    float mx = s[0];
    #pragma unroll
    for (int j = 1; j < 8; ++j) mx = fmaxf(mx, s[j]);
    #pragma unroll
    for (int off = 32; off >= 1; off >>= 1) mx = fmaxf(mx, __shfl_xor(mx, off));
    __shared__ float red[8];
    if (lane == 0) red[wave] = mx;
    __syncthreads();
    mx = fmaxf(fmaxf(red[0], red[1]), fmaxf(red[2], red[3]));

    float e[8], sum = 0.f;
    #pragma unroll
    for (int j = 0; j < 8; ++j) { e[j] = __expf(s[j] - mx); sum += e[j]; }
    #pragma unroll
    for (int off = 32; off >= 1; off >>= 1) sum += __shfl_xor(sum, off);
    if (lane == 0) red[4 + wave] = sum;
    __syncthreads();
    sum = red[4] + red[5] + red[6] + red[7];
    float inv = 1.0f / sum;

    bf16x8 ho;
    #pragma unroll
    for (int j = 0; j < 8; ++j) ho[j] = (short)f2bf(e[j] * inv);
    *(bf16x8*)hp = ho;
}

extern "C" void kernel_launch(void* const* d_in, const int* in_sizes, int n_in,
                              void* d_out, int out_size, void* d_ws, size_t ws_size,
                              hipStream_t stream)
{
    const float* x  = (const float*)d_in[0];
    const float* Wq = (const float*)d_in[1];
    const float* bq = (const float*)d_in[2];
    const float* Wk = (const float*)d_in[3];
    const float* bk = (const float*)d_in[4];
    const float* Wv = (const float*)d_in[5];
    const float* bv = (const float*)d_in[6];
    const float* Wo = (const float*)d_in[7];
    const float* bo = (const float*)d_in[8];

    char* p = (char*)d_ws;
    auto alloc = [&](size_t bytes) { char* r = p; p += (bytes + 255) & ~(size_t)255; return r; };

    const size_t XE = (size_t)ROWS * D_MODEL;     // 4,194,304
    const size_t WE = (size_t)D_MODEL * D_MODEL;  // 262,144
    const size_t SE = (size_t)BATCH * SEQ * SEQ;  // 16,777,216

    u16* xh   = (u16*)alloc(XE * 2);
    u16* xl   = (u16*)alloc(XE * 2);
    u16* whh  = (u16*)alloc(3 * WE * 2);   // concat Wq,Wk,Wv (hi)
    u16* whl  = (u16*)alloc(3 * WE * 2);   // concat (lo)
    u16* woh  = (u16*)alloc(WE * 2);
    u16* wol  = (u16*)alloc(WE * 2);
    u16* qh   = (u16*)alloc(XE * 2);
    u16* kh   = (u16*)alloc(XE * 2);
    u16* vTh  = (u16*)alloc(XE * 2);
    u16* sh   = (u16*)alloc(SE * 2);
    // att (split) aliases x's split buffers — x dead after V projection
    u16* ath = xh;
    u16* atl = xl;

    // 1. fused prep (1 launch)
    prep_kernel<<<5120, 256, 0, stream>>>(x, Wq, Wk, Wv, Wo,
                                          xh, xl, whh, whl, woh, wol);

    // 2. q/k/v projections: 3-term split, 2-buffer schedule
    gemm2<2,2,2><<<dim3(64, 8, 1), 256, 0, stream>>>(xh, xl, whh, whl, bq,
        nullptr, qh, nullptr, 512, 512, 512, 512, 0, 0, 0, 1.0f, 1);
    gemm2<2,2,2><<<dim3(64, 8, 1), 256, 0, stream>>>(xh, xl, whh + WE, whl + WE, bk,
        nullptr, kh, nullptr, 512, 512, 512, 512, 0, 0, 0, 1.0f, 1);
    gemm2<2,2,2><<<dim3(64, 8, 1), 256, 0, stream>>>(xh, xl, whh + 2*WE, whl + 2*WE, bv,
        nullptr, vTh, nullptr, 512, 512, 512, 512, 0, 0, 0, 1.0f, 2);

    // 3. scores = q@k^T * 1/sqrt(512): direct-to-register + staged epilogue
    gemm_reg<4><<<dim3(16, 16, 4), 256, 0, stream>>>(qh, kh, sh,
        512, 512, 512, 2048,
        (long)SEQ * 512, (long)SEQ * 512, (long)SEQ * SEQ,
        0.044194173824159216f);

    // 4. softmax rows (bf16 in/out)
    softmax_kernel<<<ROWS, 256, 0, stream>>>(sh);

    // 5. att = p @ v: 1-term, ring-3; split output (feeds 3-term final)
    gemm3<2,1,1><<<dim3(16, 8, 4), 256, 0, stream>>>(sh, nullptr, vTh, nullptr, nullptr,
        nullptr, ath, atl, 2048, 2048, 2048, 512,
        (long)SEQ * SEQ, (long)512 * SEQ, (long)SEQ * 512,
        1.0f, 1);

    // 6. out = att @ Wo^T + bo: 3-term, 2-buffer, fp32 out
    gemm2<2,2,2><<<dim3(64, 8, 1), 256, 0, stream>>>(ath, atl, woh, wol, bo,
        (float*)d_out, nullptr, nullptr, 512, 512, 512, 512,
        0, 0, 0, 1.0f, 0);
}

// Round 12
// 185.787 us; speedup vs baseline: 1.2534x; 1.1785x over previous
//
#include <hip/hip_runtime.h>
#include <hip/hip_bf16.h>

#define D_MODEL 512
#define BATCH 4
#define SEQ 2048
#define ROWS (BATCH*SEQ)   // 8192

typedef unsigned short u16;
typedef short bf16x8 __attribute__((ext_vector_type(8)));
typedef float f32x4 __attribute__((ext_vector_type(4)));

__device__ __forceinline__ float bf2f(u16 u) {
    union { unsigned int i; float f; } v;
    v.i = ((unsigned int)u) << 16;
    return v.f;
}
__device__ __forceinline__ u16 f2bf(float f) {
    union { float f; unsigned int i; } v;
    v.f = f;
    unsigned int x = v.i;
    unsigned int r = (x >> 16) & 1u;
    x += 0x7fffu + r;           // round-to-nearest-even
    return (u16)(x >> 16);
}

template<int N> __device__ __forceinline__ void waitv() {
    static_assert(N==0 || N==3 || N==4, "unsupported vmcnt");
    if constexpr (N == 0) asm volatile("s_waitcnt vmcnt(0)" ::: "memory");
    if constexpr (N == 3) asm volatile("s_waitcnt vmcnt(3)" ::: "memory");
    if constexpr (N == 4) asm volatile("s_waitcnt vmcnt(4)" ::: "memory");
}

// ---------------- fused prep: split x + 4 weights ----------------
__global__ __launch_bounds__(256)
void prep_kernel(const float* __restrict__ x,
                 const float* __restrict__ Wq, const float* __restrict__ Wk,
                 const float* __restrict__ Wv, const float* __restrict__ Wo,
                 u16* __restrict__ xh, u16* __restrict__ xl,
                 u16* __restrict__ whh, u16* __restrict__ whl,
                 u16* __restrict__ woh, u16* __restrict__ wol)
{
    const int blk = blockIdx.x;
    const int tid = threadIdx.x;
    const int WE = 262144;
    const float* src; u16 *dh, *dl; int i;
    if (blk < 4096) {
        src = x; dh = xh; dl = xl;
        i = (blk * 256 + tid) * 4;
    } else {
        int w = (blk - 4096) >> 8;
        src = (w == 0) ? Wq : (w == 1) ? Wk : (w == 2) ? Wv : Wo;
        dh  = (w < 3) ? whh + w * WE : woh;
        dl  = (w < 3) ? whl + w * WE : wol;
        i = (((blk - 4096) & 255) * 256 + tid) * 4;
    }
    float4 v = *(const float4*)(src + i);
    float vv[4] = { v.x, v.y, v.z, v.w };
    u16 hh[4], ll[4];
    #pragma unroll
    for (int j = 0; j < 4; ++j) {
        u16 hi = f2bf(vv[j]);
        hh[j] = hi;
        ll[j] = f2bf(vv[j] - bf2f(hi));
    }
    *(ushort4*)(dh + i) = make_ushort4(hh[0], hh[1], hh[2], hh[3]);
    *(ushort4*)(dl + i) = make_ushort4(ll[0], ll[1], ll[2], ll[3]);
}

// ======== shared GEMM pieces (128^2, 4-wave) ========
#define GEMM_PROLOG                                                            \
    constexpr int BN     = 32 * NF;                                            \
    constexpr int TILE_A = 128 * 32;                                           \
    constexpr int TILE_B = BN * 32;                                            \
    constexpr int ACH    = 8;                                                  \
    constexpr int BCH    = BN / 16;                                            \
    constexpr int NCH    = AT*ACH + BT*BCH;                                    \
    constexpr int CPW    = NCH / 4;                                            \
    constexpr int BUFSZ  = AT*TILE_A + BT*TILE_B;                              \
    const int tid  = threadIdx.x;                                              \
    const int lane = tid & 63;                                                 \
    const int wave = tid >> 6;                                                 \
    const int wr = wave >> 1, wc = wave & 1;                                   \
    const int gx = gridDim.x, gy = gridDim.y;                                  \
    int nwg = gx * gy * gridDim.z;                                             \
    int wg  = blockIdx.x + gx * (blockIdx.y + gy * blockIdx.z);                \
    int id  = (wg & 7) * (nwg >> 3) + (wg >> 3);                               \
    const int bx = id % gx;                                                    \
    const int by = (id / gx) % gy;                                             \
    const int bz = id / (gx * gy);                                             \
    const long aBase = (long)bz * aStride + (long)(bx * 128) * lda;            \
    const long bBase = (long)bz * bStride + (long)(by * BN) * ldb;             \
    const u16* csrc[CPW];                                                      \
    unsigned cdst[CPW];                                                        \
    _Pragma("unroll")                                                          \
    for (int i = 0; i < CPW; ++i) {                                            \
        int c = wave + i * 4;                                                  \
        const u16* sb; int ld, lofs, row;                                      \
        if (c < AT * ACH) {                                                    \
            int t = c >> 3;                                                    \
            row = (c & 7) * 16;                                                \
            sb = (t == 0 ? Ah : Al) + aBase;                                   \
            ld = lda; lofs = t * TILE_A;                                       \
        } else {                                                               \
            int cb = c - AT * ACH;                                             \
            int t = cb / BCH;                                                  \
            row = (cb % BCH) * 16;                                             \
            sb = (t == 0 ? Bh : Bl) + bBase;                                   \
            ld = ldb; lofs = AT * TILE_A + t * TILE_B;                         \
        }                                                                      \
        csrc[i] = sb + (long)(row + (lane >> 2)) * ld + (lane & 3) * 8;        \
        cdst[i] = lofs + row * 32;                                             \
    }                                                                          \
    f32x4 acc[4][NF] = {};                                                     \
    const int frow = lane & 15;                                                \
    const int kofs = (lane >> 4) * 8;

#define GEMM_COMPUTE(bb_)                                                      \
    {                                                                          \
        const int bb = (bb_);                                                  \
        bf16x8 aH[4], aL[4], bH[NF], bL[NF];                                   \
        _Pragma("unroll")                                                      \
        for (int m = 0; m < 4; ++m) {                                          \
            int rA = wr*64 + m*16 + frow;                                      \
            aH[m] = *(const bf16x8*)&lds[bb + rA*32 + kofs];                   \
            if constexpr (AT == 2)                                             \
                aL[m] = *(const bf16x8*)&lds[bb + TILE_A + rA*32 + kofs];      \
        }                                                                      \
        _Pragma("unroll")                                                      \
        for (int n = 0; n < NF; ++n) {                                         \
            int rB = wc*(NF*16) + n*16 + frow;                                 \
            bH[n] = *(const bf16x8*)&lds[bb + AT*TILE_A + rB*32 + kofs];       \
            if constexpr (BT == 2)                                             \
                bL[n] = *(const bf16x8*)&lds[bb + AT*TILE_A + TILE_B + rB*32 + kofs]; \
        }                                                                      \
        _Pragma("unroll")                                                      \
        for (int m = 0; m < 4; ++m)                                            \
            _Pragma("unroll")                                                  \
            for (int n = 0; n < NF; ++n) {                                     \
                acc[m][n] = __builtin_amdgcn_mfma_f32_16x16x32_bf16(aH[m], bH[n], acc[m][n], 0, 0, 0); \
                if constexpr (BT == 2)                                         \
                    acc[m][n] = __builtin_amdgcn_mfma_f32_16x16x32_bf16(aH[m], bL[n], acc[m][n], 0, 0, 0); \
                if constexpr (AT == 2)                                         \
                    acc[m][n] = __builtin_amdgcn_mfma_f32_16x16x32_bf16(aL[m], bH[n], acc[m][n], 0, 0, 0); \
            }                                                                  \
    }

#define GEMM_EPILOG_STAGED                                                     \
    {                                                                          \
    const int rr = (lane >> 4) * 4;                                            \
    __syncthreads();                                                           \
    if (mode == 0) {                                                           \
        float* ldsF = (float*)lds;                                             \
        _Pragma("unroll")                                                      \
        for (int n = 0; n < NF; ++n) {                                         \
            int c = wc*(NF*16) + n*16 + frow;                                  \
            float bv_ = bias ? bias[by*BN + c] : 0.0f;                         \
            _Pragma("unroll")                                                  \
            for (int m = 0; m < 4; ++m)                                        \
                _Pragma("unroll")                                              \
                for (int j = 0; j < 4; ++j)                                    \
                    ldsF[(wr*64 + m*16 + rr + j)*(BN+4) + c] = acc[m][n][j]*scale + bv_; \
        }                                                                      \
        __syncthreads();                                                       \
        for (int idx = tid; idx < 128*(BN/4); idx += 256) {                    \
            int row = idx / (BN/4), c4 = (idx % (BN/4)) * 4;                   \
            *(float4*)&outF[(long)bz*cStride + (long)(bx*128+row)*ldc + by*BN + c4] = \
                *(float4*)&ldsF[row*(BN+4) + c4];                              \
        }                                                                      \
    } else if (mode == 1) {                                                    \
        u16* ldsH = (u16*)lds;                                                 \
        u16* ldsL = (u16*)lds + 128*(BN+12);                                   \
        _Pragma("unroll")                                                      \
        for (int n = 0; n < NF; ++n) {                                         \
            int c = wc*(NF*16) + n*16 + frow;                                  \
            float bv_ = bias ? bias[by*BN + c] : 0.0f;                         \
            _Pragma("unroll")                                                  \
            for (int m = 0; m < 4; ++m)                                        \
                _Pragma("unroll")                                              \
                for (int j = 0; j < 4; ++j) {                                  \
                    int r = wr*64 + m*16 + rr + j;                             \
                    float val = acc[m][n][j]*scale + bv_;                      \
                    u16 h = f2bf(val);                                         \
                    ldsH[r*(BN+12) + c] = h;                                   \
                    if (outL) ldsL[r*(BN+12) + c] = f2bf(val - bf2f(h));       \
                }                                                              \
        }                                                                      \
        __syncthreads();                                                       \
        for (int idx = tid; idx < 128*(BN/8); idx += 256) {                    \
            int row = idx / (BN/8), c8 = (idx % (BN/8)) * 8;                   \
            long o = (long)bz*cStride + (long)(bx*128+row)*ldc + by*BN + c8;   \
            *(bf16x8*)&outH[o] = *(bf16x8*)&ldsH[row*(BN+12) + c8];            \
            if (outL) *(bf16x8*)&outL[o] = *(bf16x8*)&ldsL[row*(BN+12) + c8];  \
        }                                                                      \
    } else {                                                                   \
        u16* ldsT = (u16*)lds;   /* [BN][136]: transposed tile */              \
        _Pragma("unroll")                                                      \
        for (int n = 0; n < NF; ++n) {                                         \
            int c = wc*(NF*16) + n*16 + frow;                                  \
            float bv_ = bias ? bias[by*BN + c] : 0.0f;                         \
            _Pragma("unroll")                                                  \
            for (int m = 0; m < 4; ++m)                                        \
                _Pragma("unroll")                                              \
                for (int j = 0; j < 4; ++j)                                    \
                    ldsT[c*136 + (wr*64 + m*16 + rr + j)] = f2bf(acc[m][n][j]*scale + bv_); \
        }                                                                      \
        __syncthreads();                                                       \
        int b = bx >> 4, mrowBase = (bx & 15) * 128;                           \
        for (int idx = tid; idx < BN*16; idx += 256) {                         \
            int crow = idx >> 4, r8 = (idx & 15) * 8;                          \
            *(bf16x8*)&outH[(long)b*1048576 + (long)(by*BN + crow)*2048 + mrowBase + r8] = \
                *(bf16x8*)&ldsT[crow*136 + r8];                                \
        }                                                                      \
    }                                                                          \
    }

// ---- 2-buffer variant (projections, final) ----
template<int NF, int AT, int BT>
__global__ __launch_bounds__(256)
void gemm2(const u16* __restrict__ Ah, const u16* __restrict__ Al,
           const u16* __restrict__ Bh, const u16* __restrict__ Bl,
           const float* __restrict__ bias,
           float* __restrict__ outF, u16* __restrict__ outH, u16* __restrict__ outL,
           int K, int lda, int ldb, int ldc,
           long aStride, long bStride, long cStride,
           float scale, int mode)
{
    GEMM_PROLOG
    constexpr int EPI1 = 128*(BN+12);
    constexpr int EPI0 = 256*(BN+4);
    constexpr int LDSN = (2*BUFSZ > EPI1 ? (2*BUFSZ > EPI0 ? 2*BUFSZ : EPI0)
                                         : (EPI1 > EPI0 ? EPI1 : EPI0));
    __shared__ u16 lds[LDSN];
    auto stage = [&](int buf, int k0) {
        #pragma unroll
        for (int i = 0; i < CPW; ++i)
            __builtin_amdgcn_global_load_lds(
                (const __attribute__((address_space(1))) unsigned int*)(csrc[i] + k0),
                (__attribute__((address_space(3))) unsigned int*)(&lds[buf * BUFSZ + cdst[i]]),
                16, 0, 0);
    };
    const int nt = K >> 5;
    stage(0, 0);
    __syncthreads();
    int cur = 0;
    for (int t = 0; t < nt; ++t) {
        if (t + 1 < nt) stage(cur ^ 1, (t + 1) << 5);
        GEMM_COMPUTE(cur * BUFSZ)
        __syncthreads();
        cur ^= 1;
    }
    GEMM_EPILOG_STAGED
}

// ---- ring-3 counted-vmcnt variant (PV) ----
template<int NF, int AT, int BT>
__global__ __launch_bounds__(256)
void gemm3(const u16* __restrict__ Ah, const u16* __restrict__ Al,
           const u16* __restrict__ Bh, const u16* __restrict__ Bl,
           const float* __restrict__ bias,
           float* __restrict__ outF, u16* __restrict__ outH, u16* __restrict__ outL,
           int K, int lda, int ldb, int ldc,
           long aStride, long bStride, long cStride,
           float scale, int mode)
{
    GEMM_PROLOG
    constexpr int EPI1 = 256*(BN+12);
    constexpr int LDSN = (3*BUFSZ > EPI1) ? 3*BUFSZ : EPI1;
    __shared__ u16 lds[LDSN];
    auto stage = [&](int buf, int k0) {
        #pragma unroll
        for (int i = 0; i < CPW; ++i)
            __builtin_amdgcn_global_load_lds(
                (const __attribute__((address_space(1))) unsigned int*)(csrc[i] + k0),
                (__attribute__((address_space(3))) unsigned int*)(&lds[buf * BUFSZ + cdst[i]]),
                16, 0, 0);
    };
    const int nt = K >> 5;
    stage(0, 0);
    stage(1, 32);
    for (int t = 0; t < nt; ++t) {
        if (t + 1 < nt) waitv<CPW>();
        else            waitv<0>();
        __builtin_amdgcn_s_barrier();
        __builtin_amdgcn_sched_barrier(0);
        if (t + 2 < nt) stage((t + 2) % 3, (t + 2) << 5);
        GEMM_COMPUTE((t % 3) * BUFSZ)
    }
    GEMM_EPILOG_STAGED
}

// ---- 256x256 tile, 8-wave (2x4), 2-buffer schedule (scores) ----
// m112-class geometry: per-wave 128x64 output, BK=32. bf16 in/out.
__global__ __launch_bounds__(512)
void gemm256(const u16* __restrict__ A, const u16* __restrict__ B,
             u16* __restrict__ outH,
             int K, int lda, int ldb, int ldc,
             long aStride, long bStride, long cStride, float scale)
{
    __shared__ u16 lds[2 * 16384];          // 2 bufs x (A[256][32] + B[256][32])
    const int tid  = threadIdx.x;
    const int lane = tid & 63;
    const int wave = tid >> 6;              // 0..7
    const int wr = wave >> 2, wc = wave & 3;

    // XCD-aware swizzle (grid %8==0)
    const int gx = gridDim.x, gy = gridDim.y;
    int nwg = gx * gy * gridDim.z;
    int wg  = blockIdx.x + gx * (blockIdx.y + gy * blockIdx.z);
    int id  = (wg & 7) * (nwg >> 3) + (wg >> 3);
    const int bx = id % gx;
    const int by = (id / gx) % gy;
    const int bz = id / (gx * gy);

    const long aBase = (long)bz * aStride + (long)(bx * 256) * lda;
    const long bBase = (long)bz * bStride + (long)(by * 256) * ldb;

    // staging: 32 chunks (16 A + 16 B) of 16 rows x 32 elems; 4 per wave
    const u16* csrc[4];
    unsigned cdst[4];
    #pragma unroll
    for (int i = 0; i < 4; ++i) {
        int c = wave + i * 8;               // 0..31
        int t = c >> 4;                     // 0 = A, 1 = B
        int row16 = c & 15;
        const u16* sb = t ? (B + bBase) : (A + aBase);
        int ld = t ? ldb : lda;
        csrc[i] = sb + (long)(row16 * 16 + (lane >> 2)) * ld + (lane & 3) * 8;
        cdst[i] = t * 8192 + row16 * 512;
    }
    auto stage = [&](int buf, int k0) {
        #pragma unroll
        for (int i = 0; i < 4; ++i)
            __builtin_amdgcn_global_load_lds(
                (const __attribute__((address_space(1))) unsigned int*)(csrc[i] + k0),
                (__attribute__((address_space(3))) unsigned int*)(&lds[buf * 16384 + cdst[i]]),
                16, 0, 0);
    };

    f32x4 acc[8][4] = {};
    const int frow = lane & 15;
    const int kofs = (lane >> 4) * 8;

    const int nt = K >> 5;
    stage(0, 0);
    __syncthreads();
    int cur = 0;
    for (int t = 0; t < nt; ++t) {
        if (t + 1 < nt) stage(cur ^ 1, (t + 1) << 5);
        const int bb = cur * 16384;
        bf16x8 aH[8], bH[4];
        #pragma unroll
        for (int m = 0; m < 8; ++m) {
            int rA = wr*128 + m*16 + frow;
            aH[m] = *(const bf16x8*)&lds[bb + rA*32 + kofs];
        }
        #pragma unroll
        for (int n = 0; n < 4; ++n) {
            int rB = wc*64 + n*16 + frow;
            bH[n] = *(const bf16x8*)&lds[bb + 8192 + rB*32 + kofs];
        }
        #pragma unroll
        for (int m = 0; m < 8; ++m)
            #pragma unroll
            for (int n = 0; n < 4; ++n)
                acc[m][n] = __builtin_amdgcn_mfma_f32_16x16x32_bf16(aH[m], bH[n], acc[m][n], 0, 0, 0);
        __syncthreads();
        cur ^= 1;
    }

    // epilogue: direct stores (measured ~equal to staged for scores)
    const int rr = (lane >> 4) * 4;
    #pragma unroll
    for (int n = 0; n < 4; ++n) {
        int colL = by*256 + wc*64 + n*16 + frow;
        #pragma unroll
        for (int m = 0; m < 8; ++m) {
            #pragma unroll
            for (int j = 0; j < 4; ++j) {
                int rowL = bx*256 + wr*128 + m*16 + rr + j;
                outH[(long)bz*cStride + (long)rowL*ldc + colL] = f2bf(acc[m][n][j] * scale);
            }
        }
    }
}

// ---------------- row softmax over 2048, in-place, bf16 ----------------
__global__ __launch_bounds__(256)
void softmax_kernel(u16* __restrict__ sh)
{
    const long base = (long)blockIdx.x * 2048;
    const int tid = threadIdx.x;
    const int lane = tid & 63, wave = tid >> 6;
    u16* hp = sh + base + tid * 8;
    bf16x8 hv = *(const bf16x8*)hp;
    float s[8];
    #pragma unroll
    for (int j = 0; j < 8; ++j) s[j] = bf2f((u16)hv[j]);

    float mx = s[0];
    #pragma unroll
    for (int j = 1; j < 8; ++j) mx = fmaxf(mx, s[j]);
    #pragma unroll
    for (int off = 32; off >= 1; off >>= 1) mx = fmaxf(mx, __shfl_xor(mx, off));
    __shared__ float red[8];
    if (lane == 0) red[wave] = mx;
    __syncthreads();
    mx = fmaxf(fmaxf(red[0], red[1]), fmaxf(red[2], red[3]));

    float e[8], sum = 0.f;
    #pragma unroll
    for (int j = 0; j < 8; ++j) { e[j] = __expf(s[j] - mx); sum += e[j]; }
    #pragma unroll
    for (int off = 32; off >= 1; off >>= 1) sum += __shfl_xor(sum, off);
    if (lane == 0) red[4 + wave] = sum;
    __syncthreads();
    sum = red[4] + red[5] + red[6] + red[7];
    float inv = 1.0f / sum;

    bf16x8 ho;
    #pragma unroll
    for (int j = 0; j < 8; ++j) ho[j] = (short)f2bf(e[j] * inv);
    *(bf16x8*)hp = ho;
}

extern "C" void kernel_launch(void* const* d_in, const int* in_sizes, int n_in,
                              void* d_out, int out_size, void* d_ws, size_t ws_size,
                              hipStream_t stream)
{
    const float* x  = (const float*)d_in[0];
    const float* Wq = (const float*)d_in[1];
    const float* bq = (const float*)d_in[2];
    const float* Wk = (const float*)d_in[3];
    const float* bk = (const float*)d_in[4];
    const float* Wv = (const float*)d_in[5];
    const float* bv = (const float*)d_in[6];
    const float* Wo = (const float*)d_in[7];
    const float* bo = (const float*)d_in[8];

    char* p = (char*)d_ws;
    auto alloc = [&](size_t bytes) { char* r = p; p += (bytes + 255) & ~(size_t)255; return r; };

    const size_t XE = (size_t)ROWS * D_MODEL;     // 4,194,304
    const size_t WE = (size_t)D_MODEL * D_MODEL;  // 262,144
    const size_t SE = (size_t)BATCH * SEQ * SEQ;  // 16,777,216

    u16* xh   = (u16*)alloc(XE * 2);
    u16* xl   = (u16*)alloc(XE * 2);
    u16* whh  = (u16*)alloc(3 * WE * 2);   // concat Wq,Wk,Wv (hi)
    u16* whl  = (u16*)alloc(3 * WE * 2);   // concat (lo)
    u16* woh  = (u16*)alloc(WE * 2);
    u16* wol  = (u16*)alloc(WE * 2);
    u16* qh   = (u16*)alloc(XE * 2);
    u16* kh   = (u16*)alloc(XE * 2);
    u16* vTh  = (u16*)alloc(XE * 2);
    u16* sh   = (u16*)alloc(SE * 2);
    // att (split) aliases x's split buffers — x dead after V projection
    u16* ath = xh;
    u16* atl = xl;

    // 1. fused prep (1 launch)
    prep_kernel<<<5120, 256, 0, stream>>>(x, Wq, Wk, Wv, Wo,
                                          xh, xl, whh, whl, woh, wol);

    // 2. q/k/v projections: 3-term split, 2-buffer schedule
    gemm2<2,2,2><<<dim3(64, 8, 1), 256, 0, stream>>>(xh, xl, whh, whl, bq,
        nullptr, qh, nullptr, 512, 512, 512, 512, 0, 0, 0, 1.0f, 1);
    gemm2<2,2,2><<<dim3(64, 8, 1), 256, 0, stream>>>(xh, xl, whh + WE, whl + WE, bk,
        nullptr, kh, nullptr, 512, 512, 512, 512, 0, 0, 0, 1.0f, 1);
    gemm2<2,2,2><<<dim3(64, 8, 1), 256, 0, stream>>>(xh, xl, whh + 2*WE, whl + 2*WE, bv,
        nullptr, vTh, nullptr, 512, 512, 512, 512, 0, 0, 0, 1.0f, 2);

    // 3. scores = q@k^T * 1/sqrt(512): 256^2 tile, 8-wave
    gemm256<<<dim3(8, 8, 4), 512, 0, stream>>>(qh, kh, sh,
        512, 512, 512, 2048,
        (long)SEQ * 512, (long)SEQ * 512, (long)SEQ * SEQ,
        0.044194173824159216f);

    // 4. softmax rows (bf16 in/out)
    softmax_kernel<<<ROWS, 256, 0, stream>>>(sh);

    // 5. att = p @ v: 1-term, ring-3; split output (feeds 3-term final)
    gemm3<2,1,1><<<dim3(16, 8, 4), 256, 0, stream>>>(sh, nullptr, vTh, nullptr, nullptr,
        nullptr, ath, atl, 2048, 2048, 2048, 512,
        (long)SEQ * SEQ, (long)512 * SEQ, (long)SEQ * 512,
        1.0f, 1);

    // 6. out = att @ Wo^T + bo: 3-term, 2-buffer, fp32 out
    gemm2<2,2,2><<<dim3(64, 8, 1), 256, 0, stream>>>(ath, atl, woh, wol, bo,
        (float*)d_out, nullptr, nullptr, 512, 512, 512, 512,
        0, 0, 0, 1.0f, 0);
}

// Round 14
// 184.139 us; speedup vs baseline: 1.2646x; 1.0090x over previous
//
#include <hip/hip_runtime.h>
#include <hip/hip_bf16.h>

#define D_MODEL 512
#define BATCH 4
#define SEQ 2048
#define ROWS (BATCH*SEQ)   // 8192

typedef unsigned short u16;
typedef short bf16x8 __attribute__((ext_vector_type(8)));
typedef float f32x4 __attribute__((ext_vector_type(4)));

__device__ __forceinline__ float bf2f(u16 u) {
    union { unsigned int i; float f; } v;
    v.i = ((unsigned int)u) << 16;
    return v.f;
}
__device__ __forceinline__ u16 f2bf(float f) {
    union { float f; unsigned int i; } v;
    v.f = f;
    unsigned int x = v.i;
    unsigned int r = (x >> 16) & 1u;
    x += 0x7fffu + r;           // round-to-nearest-even
    return (u16)(x >> 16);
}

template<int N> __device__ __forceinline__ void waitv() {
    static_assert(N==0 || N==3 || N==4, "unsupported vmcnt");
    if constexpr (N == 0) asm volatile("s_waitcnt vmcnt(0)" ::: "memory");
    if constexpr (N == 3) asm volatile("s_waitcnt vmcnt(3)" ::: "memory");
    if constexpr (N == 4) asm volatile("s_waitcnt vmcnt(4)" ::: "memory");
}

// ---------------- fused prep: split x + 4 weights ----------------
__global__ __launch_bounds__(256)
void prep_kernel(const float* __restrict__ x,
                 const float* __restrict__ Wq, const float* __restrict__ Wk,
                 const float* __restrict__ Wv, const float* __restrict__ Wo,
                 u16* __restrict__ xh, u16* __restrict__ xl,
                 u16* __restrict__ whh, u16* __restrict__ whl,
                 u16* __restrict__ woh, u16* __restrict__ wol)
{
    const int blk = blockIdx.x;
    const int tid = threadIdx.x;
    const int WE = 262144;
    const float* src; u16 *dh, *dl; int i;
    if (blk < 4096) {
        src = x; dh = xh; dl = xl;
        i = (blk * 256 + tid) * 4;
    } else {
        int w = (blk - 4096) >> 8;
        src = (w == 0) ? Wq : (w == 1) ? Wk : (w == 2) ? Wv : Wo;
        dh  = (w < 3) ? whh + w * WE : woh;
        dl  = (w < 3) ? whl + w * WE : wol;
        i = (((blk - 4096) & 255) * 256 + tid) * 4;
    }
    float4 v = *(const float4*)(src + i);
    float vv[4] = { v.x, v.y, v.z, v.w };
    u16 hh[4], ll[4];
    #pragma unroll
    for (int j = 0; j < 4; ++j) {
        u16 hi = f2bf(vv[j]);
        hh[j] = hi;
        ll[j] = f2bf(vv[j] - bf2f(hi));
    }
    *(ushort4*)(dh + i) = make_ushort4(hh[0], hh[1], hh[2], hh[3]);
    *(ushort4*)(dl + i) = make_ushort4(ll[0], ll[1], ll[2], ll[3]);
}

// ======== shared GEMM pieces (128^2, 4-wave) ========
#define GEMM_PROLOG                                                            \
    constexpr int BN     = 32 * NF;                                            \
    constexpr int TILE_A = 128 * 32;                                           \
    constexpr int TILE_B = BN * 32;                                            \
    constexpr int ACH    = 8;                                                  \
    constexpr int BCH    = BN / 16;                                            \
    constexpr int NCH    = AT*ACH + BT*BCH;                                    \
    constexpr int CPW    = NCH / 4;                                            \
    constexpr int BUFSZ  = AT*TILE_A + BT*TILE_B;                              \
    const int tid  = threadIdx.x;                                              \
    const int lane = tid & 63;                                                 \
    const int wave = tid >> 6;                                                 \
    const int wr = wave >> 1, wc = wave & 1;                                   \
    const int gx = gridDim.x, gy = gridDim.y;                                  \
    int nwg = gx * gy * gridDim.z;                                             \
    int wg  = blockIdx.x + gx * (blockIdx.y + gy * blockIdx.z);                \
    int id  = (wg & 7) * (nwg >> 3) + (wg >> 3);                               \
    const int bx = id % gx;                                                    \
    const int by = (id / gx) % gy;                                             \
    const int bz = id / (gx * gy);                                             \
    const long aBase = (long)bz * aStride + (long)(bx * 128) * lda;            \
    const long bBase = (long)bz * bStride + (long)(by * BN) * ldb;             \
    const u16* csrc[CPW];                                                      \
    unsigned cdst[CPW];                                                        \
    _Pragma("unroll")                                                          \
    for (int i = 0; i < CPW; ++i) {                                            \
        int c = wave + i * 4;                                                  \
        const u16* sb; int ld, lofs, row;                                      \
        if (c < AT * ACH) {                                                    \
            int t = c >> 3;                                                    \
            row = (c & 7) * 16;                                                \
            sb = (t == 0 ? Ah : Al) + aBase;                                   \
            ld = lda; lofs = t * TILE_A;                                       \
        } else {                                                               \
            int cb = c - AT * ACH;                                             \
            int t = cb / BCH;                                                  \
            row = (cb % BCH) * 16;                                             \
            sb = (t == 0 ? Bh : Bl) + bBase;                                   \
            ld = ldb; lofs = AT * TILE_A + t * TILE_B;                         \
        }                                                                      \
        csrc[i] = sb + (long)(row + (lane >> 2)) * ld + (lane & 3) * 8;        \
        cdst[i] = lofs + row * 32;                                             \
    }                                                                          \
    f32x4 acc[4][NF] = {};                                                     \
    const int frow = lane & 15;                                                \
    const int kofs = (lane >> 4) * 8;

#define GEMM_COMPUTE(bb_)                                                      \
    {                                                                          \
        const int bb = (bb_);                                                  \
        bf16x8 aH[4], aL[4], bH[NF], bL[NF];                                   \
        _Pragma("unroll")                                                      \
        for (int m = 0; m < 4; ++m) {                                          \
            int rA = wr*64 + m*16 + frow;                                      \
            aH[m] = *(const bf16x8*)&lds[bb + rA*32 + kofs];                   \
            if constexpr (AT == 2)                                             \
                aL[m] = *(const bf16x8*)&lds[bb + TILE_A + rA*32 + kofs];      \
        }                                                                      \
        _Pragma("unroll")                                                      \
        for (int n = 0; n < NF; ++n) {                                         \
            int rB = wc*(NF*16) + n*16 + frow;                                 \
            bH[n] = *(const bf16x8*)&lds[bb + AT*TILE_A + rB*32 + kofs];       \
            if constexpr (BT == 2)                                             \
                bL[n] = *(const bf16x8*)&lds[bb + AT*TILE_A + TILE_B + rB*32 + kofs]; \
        }                                                                      \
        _Pragma("unroll")                                                      \
        for (int m = 0; m < 4; ++m)                                            \
            _Pragma("unroll")                                                  \
            for (int n = 0; n < NF; ++n) {                                     \
                acc[m][n] = __builtin_amdgcn_mfma_f32_16x16x32_bf16(aH[m], bH[n], acc[m][n], 0, 0, 0); \
                if constexpr (BT == 2)                                         \
                    acc[m][n] = __builtin_amdgcn_mfma_f32_16x16x32_bf16(aH[m], bL[n], acc[m][n], 0, 0, 0); \
                if constexpr (AT == 2)                                         \
                    acc[m][n] = __builtin_amdgcn_mfma_f32_16x16x32_bf16(aL[m], bH[n], acc[m][n], 0, 0, 0); \
            }                                                                  \
    }

#define GEMM_EPILOG_STAGED                                                     \
    {                                                                          \
    const int rr = (lane >> 4) * 4;                                            \
    __syncthreads();                                                           \
    if (mode == 0) {                                                           \
        float* ldsF = (float*)lds;                                             \
        _Pragma("unroll")                                                      \
        for (int n = 0; n < NF; ++n) {                                         \
            int c = wc*(NF*16) + n*16 + frow;                                  \
            float bv_ = bias ? bias[by*BN + c] : 0.0f;                         \
            _Pragma("unroll")                                                  \
            for (int m = 0; m < 4; ++m)                                        \
                _Pragma("unroll")                                              \
                for (int j = 0; j < 4; ++j)                                    \
                    ldsF[(wr*64 + m*16 + rr + j)*(BN+4) + c] = acc[m][n][j]*scale + bv_; \
        }                                                                      \
        __syncthreads();                                                       \
        for (int idx = tid; idx < 128*(BN/4); idx += 256) {                    \
            int row = idx / (BN/4), c4 = (idx % (BN/4)) * 4;                   \
            *(float4*)&outF[(long)bz*cStride + (long)(bx*128+row)*ldc + by*BN + c4] = \
                *(float4*)&ldsF[row*(BN+4) + c4];                              \
        }                                                                      \
    } else if (mode == 1) {                                                    \
        u16* ldsH = (u16*)lds;                                                 \
        u16* ldsL = (u16*)lds + 128*(BN+12);                                   \
        _Pragma("unroll")                                                      \
        for (int n = 0; n < NF; ++n) {                                         \
            int c = wc*(NF*16) + n*16 + frow;                                  \
            float bv_ = bias ? bias[by*BN + c] : 0.0f;                         \
            _Pragma("unroll")                                                  \
            for (int m = 0; m < 4; ++m)                                        \
                _Pragma("unroll")                                              \
                for (int j = 0; j < 4; ++j) {                                  \
                    int r = wr*64 + m*16 + rr + j;                             \
                    float val = acc[m][n][j]*scale + bv_;                      \
                    u16 h = f2bf(val);                                         \
                    ldsH[r*(BN+12) + c] = h;                                   \
                    if (outL) ldsL[r*(BN+12) + c] = f2bf(val - bf2f(h));       \
                }                                                              \
        }                                                                      \
        __syncthreads();                                                       \
        for (int idx = tid; idx < 128*(BN/8); idx += 256) {                    \
            int row = idx / (BN/8), c8 = (idx % (BN/8)) * 8;                   \
            long o = (long)bz*cStride + (long)(bx*128+row)*ldc + by*BN + c8;   \
            *(bf16x8*)&outH[o] = *(bf16x8*)&ldsH[row*(BN+12) + c8];            \
            if (outL) *(bf16x8*)&outL[o] = *(bf16x8*)&ldsL[row*(BN+12) + c8];  \
        }                                                                      \
    } else {                                                                   \
        u16* ldsT = (u16*)lds;   /* [BN][136]: transposed tile */              \
        _Pragma("unroll")                                                      \
        for (int n = 0; n < NF; ++n) {                                         \
            int c = wc*(NF*16) + n*16 + frow;                                  \
            float bv_ = bias ? bias[by*BN + c] : 0.0f;                         \
            _Pragma("unroll")                                                  \
            for (int m = 0; m < 4; ++m)                                        \
                _Pragma("unroll")                                              \
                for (int j = 0; j < 4; ++j)                                    \
                    ldsT[c*136 + (wr*64 + m*16 + rr + j)] = f2bf(acc[m][n][j]*scale + bv_); \
        }                                                                      \
        __syncthreads();                                                       \
        int b = bx >> 4, mrowBase = (bx & 15) * 128;                           \
        for (int idx = tid; idx < BN*16; idx += 256) {                         \
            int crow = idx >> 4, r8 = (idx & 15) * 8;                          \
            *(bf16x8*)&outH[(long)b*1048576 + (long)(by*BN + crow)*2048 + mrowBase + r8] = \
                *(bf16x8*)&ldsT[crow*136 + r8];                                \
        }                                                                      \
    }                                                                          \
    }

// ---- 2-buffer variant (projections, final) ----
template<int NF, int AT, int BT>
__global__ __launch_bounds__(256)
void gemm2(const u16* __restrict__ Ah, const u16* __restrict__ Al,
           const u16* __restrict__ Bh, const u16* __restrict__ Bl,
           const float* __restrict__ bias,
           float* __restrict__ outF, u16* __restrict__ outH, u16* __restrict__ outL,
           int K, int lda, int ldb, int ldc,
           long aStride, long bStride, long cStride,
           float scale, int mode)
{
    GEMM_PROLOG
    constexpr int EPI1 = 128*(BN+12);
    constexpr int EPI0 = 256*(BN+4);
    constexpr int LDSN = (2*BUFSZ > EPI1 ? (2*BUFSZ > EPI0 ? 2*BUFSZ : EPI0)
                                         : (EPI1 > EPI0 ? EPI1 : EPI0));
    __shared__ u16 lds[LDSN];
    auto stage = [&](int buf, int k0) {
        #pragma unroll
        for (int i = 0; i < CPW; ++i)
            __builtin_amdgcn_global_load_lds(
                (const __attribute__((address_space(1))) unsigned int*)(csrc[i] + k0),
                (__attribute__((address_space(3))) unsigned int*)(&lds[buf * BUFSZ + cdst[i]]),
                16, 0, 0);
    };
    const int nt = K >> 5;
    stage(0, 0);
    __syncthreads();
    int cur = 0;
    for (int t = 0; t < nt; ++t) {
        if (t + 1 < nt) stage(cur ^ 1, (t + 1) << 5);
        GEMM_COMPUTE(cur * BUFSZ)
        __syncthreads();
        cur ^= 1;
    }
    GEMM_EPILOG_STAGED
}

// ---- ring-3 counted-vmcnt variant (PV) ----
template<int NF, int AT, int BT>
__global__ __launch_bounds__(256)
void gemm3(const u16* __restrict__ Ah, const u16* __restrict__ Al,
           const u16* __restrict__ Bh, const u16* __restrict__ Bl,
           const float* __restrict__ bias,
           float* __restrict__ outF, u16* __restrict__ outH, u16* __restrict__ outL,
           int K, int lda, int ldb, int ldc,
           long aStride, long bStride, long cStride,
           float scale, int mode)
{
    GEMM_PROLOG
    constexpr int EPI1 = 256*(BN+12);
    constexpr int LDSN = (3*BUFSZ > EPI1) ? 3*BUFSZ : EPI1;
    __shared__ u16 lds[LDSN];
    auto stage = [&](int buf, int k0) {
        #pragma unroll
        for (int i = 0; i < CPW; ++i)
            __builtin_amdgcn_global_load_lds(
                (const __attribute__((address_space(1))) unsigned int*)(csrc[i] + k0),
                (__attribute__((address_space(3))) unsigned int*)(&lds[buf * BUFSZ + cdst[i]]),
                16, 0, 0);
    };
    const int nt = K >> 5;
    stage(0, 0);
    stage(1, 32);
    for (int t = 0; t < nt; ++t) {
        if (t + 1 < nt) waitv<CPW>();
        else            waitv<0>();
        __builtin_amdgcn_s_barrier();
        __builtin_amdgcn_sched_barrier(0);
        if (t + 2 < nt) stage((t + 2) % 3, (t + 2) << 5);
        GEMM_COMPUTE((t % 3) * BUFSZ)
    }
    GEMM_EPILOG_STAGED
}

// ---- 256x256 tile, 8-wave (2x4), 2-buffer schedule + STAGED epilogue ----
__global__ __launch_bounds__(512)
void gemm256(const u16* __restrict__ A, const u16* __restrict__ B,
             u16* __restrict__ outH,
             int K, int lda, int ldb, int ldc,
             long aStride, long bStride, long cStride, float scale)
{
    // K-loop: 2 bufs x 16384 u16 (64 KB). Epilogue reuses as [128][264] (67.6 KB).
    __shared__ u16 lds[33792];
    const int tid  = threadIdx.x;
    const int lane = tid & 63;
    const int wave = tid >> 6;              // 0..7
    const int wr = wave >> 2, wc = wave & 3;

    // XCD-aware swizzle (grid %8==0)
    const int gx = gridDim.x, gy = gridDim.y;
    int nwg = gx * gy * gridDim.z;
    int wg  = blockIdx.x + gx * (blockIdx.y + gy * blockIdx.z);
    int id  = (wg & 7) * (nwg >> 3) + (wg >> 3);
    const int bx = id % gx;
    const int by = (id / gx) % gy;
    const int bz = id / (gx * gy);

    const long aBase = (long)bz * aStride + (long)(bx * 256) * lda;
    const long bBase = (long)bz * bStride + (long)(by * 256) * ldb;

    // staging: 32 chunks (16 A + 16 B) of 16 rows x 32 elems; 4 per wave
    const u16* csrc[4];
    unsigned cdst[4];
    #pragma unroll
    for (int i = 0; i < 4; ++i) {
        int c = wave + i * 8;               // 0..31
        int t = c >> 4;                     // 0 = A, 1 = B
        int row16 = c & 15;
        const u16* sb = t ? (B + bBase) : (A + aBase);
        int ld = t ? ldb : lda;
        csrc[i] = sb + (long)(row16 * 16 + (lane >> 2)) * ld + (lane & 3) * 8;
        cdst[i] = t * 8192 + row16 * 512;
    }
    auto stage = [&](int buf, int k0) {
        #pragma unroll
        for (int i = 0; i < 4; ++i)
            __builtin_amdgcn_global_load_lds(
                (const __attribute__((address_space(1))) unsigned int*)(csrc[i] + k0),
                (__attribute__((address_space(3))) unsigned int*)(&lds[buf * 16384 + cdst[i]]),
                16, 0, 0);
    };

    f32x4 acc[8][4] = {};
    const int frow = lane & 15;
    const int kofs = (lane >> 4) * 8;

    const int nt = K >> 5;
    stage(0, 0);
    __syncthreads();
    int cur = 0;
    for (int t = 0; t < nt; ++t) {
        if (t + 1 < nt) stage(cur ^ 1, (t + 1) << 5);
        const int bb = cur * 16384;
        bf16x8 aH[8], bH[4];
        #pragma unroll
        for (int m = 0; m < 8; ++m) {
            int rA = wr*128 + m*16 + frow;
            aH[m] = *(const bf16x8*)&lds[bb + rA*32 + kofs];
        }
        #pragma unroll
        for (int n = 0; n < 4; ++n) {
            int rB = wc*64 + n*16 + frow;
            bH[n] = *(const bf16x8*)&lds[bb + 8192 + rB*32 + kofs];
        }
        #pragma unroll
        for (int m = 0; m < 8; ++m)
            #pragma unroll
            for (int n = 0; n < 4; ++n)
                acc[m][n] = __builtin_amdgcn_mfma_f32_16x16x32_bf16(aH[m], bH[n], acc[m][n], 0, 0, 0);
        __syncthreads();
        cur ^= 1;
    }

    // staged epilogue: two half-tiles through LDS [128][264], coalesced stores
    const int rr = (lane >> 4) * 4;
    #pragma unroll
    for (int h = 0; h < 2; ++h) {
        __syncthreads();
        if (wr == h) {
            #pragma unroll
            for (int n = 0; n < 4; ++n) {
                int c = wc*64 + n*16 + frow;
                #pragma unroll
                for (int m = 0; m < 8; ++m)
                    #pragma unroll
                    for (int j = 0; j < 4; ++j)
                        lds[(m*16 + rr + j)*264 + c] = f2bf(acc[m][n][j] * scale);
            }
        }
        __syncthreads();
        for (int idx = tid; idx < 128*32; idx += 512) {
            int row = idx >> 5, c8 = (idx & 31) * 8;
            *(bf16x8*)&outH[(long)bz*cStride + (long)(bx*256 + h*128 + row)*ldc + by*256 + c8] =
                *(bf16x8*)&lds[row*264 + c8];
        }
    }
}

// ---------------- row softmax over 2048, in-place, bf16 ----------------
__global__ __launch_bounds__(256)
void softmax_kernel(u16* __restrict__ sh)
{
    const long base = (long)blockIdx.x * 2048;
    const int tid = threadIdx.x;
    const int lane = tid & 63, wave = tid >> 6;
    u16* hp = sh + base + tid * 8;
    bf16x8 hv = *(const bf16x8*)hp;
    float s[8];
    #pragma unroll
    for (int j = 0; j < 8; ++j) s[j] = bf2f((u16)hv[j]);

    float mx = s[0];
    #pragma unroll
    for (int j = 1; j < 8; ++j) mx = fmaxf(mx, s[j]);
    #pragma unroll
    for (int off = 32; off >= 1; off >>= 1) mx = fmaxf(mx, __shfl_xor(mx, off));
    __shared__ float red[8];
    if (lane == 0) red[wave] = mx;
    __syncthreads();
    mx = fmaxf(fmaxf(red[0], red[1]), fmaxf(red[2], red[3]));

    float e[8], sum = 0.f;
    #pragma unroll
    for (int j = 0; j < 8; ++j) { e[j] = __expf(s[j] - mx); sum += e[j]; }
    #pragma unroll
    for (int off = 32; off >= 1; off >>= 1) sum += __shfl_xor(sum, off);
    if (lane == 0) red[4 + wave] = sum;
    __syncthreads();
    sum = red[4] + red[5] + red[6] + red[7];
    float inv = 1.0f / sum;

    bf16x8 ho;
    #pragma unroll
    for (int j = 0; j < 8; ++j) ho[j] = (short)f2bf(e[j] * inv);
    *(bf16x8*)hp = ho;
}

extern "C" void kernel_launch(void* const* d_in, const int* in_sizes, int n_in,
                              void* d_out, int out_size, void* d_ws, size_t ws_size,
                              hipStream_t stream)
{
    const float* x  = (const float*)d_in[0];
    const float* Wq = (const float*)d_in[1];
    const float* bq = (const float*)d_in[2];
    const float* Wk = (const float*)d_in[3];
    const float* bk = (const float*)d_in[4];
    const float* Wv = (const float*)d_in[5];
    const float* bv = (const float*)d_in[6];
    const float* Wo = (const float*)d_in[7];
    const float* bo = (const float*)d_in[8];

    char* p = (char*)d_ws;
    auto alloc = [&](size_t bytes) { char* r = p; p += (bytes + 255) & ~(size_t)255; return r; };

    const size_t XE = (size_t)ROWS * D_MODEL;     // 4,194,304
    const size_t WE = (size_t)D_MODEL * D_MODEL;  // 262,144
    const size_t SE = (size_t)BATCH * SEQ * SEQ;  // 16,777,216

    u16* xh   = (u16*)alloc(XE * 2);
    u16* xl   = (u16*)alloc(XE * 2);
    u16* whh  = (u16*)alloc(3 * WE * 2);   // concat Wq,Wk,Wv (hi)
    u16* whl  = (u16*)alloc(3 * WE * 2);   // concat (lo)
    u16* woh  = (u16*)alloc(WE * 2);
    u16* wol  = (u16*)alloc(WE * 2);
    u16* qh   = (u16*)alloc(XE * 2);
    u16* kh   = (u16*)alloc(XE * 2);
    u16* vTh  = (u16*)alloc(XE * 2);
    u16* sh   = (u16*)alloc(SE * 2);
    // att (split) aliases x's split buffers — x dead after V projection
    u16* ath = xh;
    u16* atl = xl;

    // 1. fused prep (1 launch)
    prep_kernel<<<5120, 256, 0, stream>>>(x, Wq, Wk, Wv, Wo,
                                          xh, xl, whh, whl, woh, wol);

    // 2. q/k/v projections: 3-term split, 2-buffer schedule
    gemm2<2,2,2><<<dim3(64, 8, 1), 256, 0, stream>>>(xh, xl, whh, whl, bq,
        nullptr, qh, nullptr, 512, 512, 512, 512, 0, 0, 0, 1.0f, 1);
    gemm2<2,2,2><<<dim3(64, 8, 1), 256, 0, stream>>>(xh, xl, whh + WE, whl + WE, bk,
        nullptr, kh, nullptr, 512, 512, 512, 512, 0, 0, 0, 1.0f, 1);
    gemm2<2,2,2><<<dim3(64, 8, 1), 256, 0, stream>>>(xh, xl, whh + 2*WE, whl + 2*WE, bv,
        nullptr, vTh, nullptr, 512, 512, 512, 512, 0, 0, 0, 1.0f, 2);

    // 3. scores = q@k^T * 1/sqrt(512): 256^2 tile, 8-wave, staged epilogue
    gemm256<<<dim3(8, 8, 4), 512, 0, stream>>>(qh, kh, sh,
        512, 512, 512, 2048,
        (long)SEQ * 512, (long)SEQ * 512, (long)SEQ * SEQ,
        0.044194173824159216f);

    // 4. softmax rows (bf16 in/out)
    softmax_kernel<<<ROWS, 256, 0, stream>>>(sh);

    // 5. att = p @ v: 1-term, ring-3; split output (feeds 3-term final)
    gemm3<2,1,1><<<dim3(16, 8, 4), 256, 0, stream>>>(sh, nullptr, vTh, nullptr, nullptr,
        nullptr, ath, atl, 2048, 2048, 2048, 512,
        (long)SEQ * SEQ, (long)512 * SEQ, (long)SEQ * 512,
        1.0f, 1);

    // 6. out = att @ Wo^T + bo: 3-term, 2-buffer, fp32 out
    gemm2<2,2,2><<<dim3(64, 8, 1), 256, 0, stream>>>(ath, atl, woh, wol, bo,
        (float*)d_out, nullptr, nullptr, 512, 512, 512, 512,
        0, 0, 0, 1.0f, 0);
}

// Round 16
// 181.982 us; speedup vs baseline: 1.2796x; 1.0119x over previous
//
#include <hip/hip_runtime.h>
#include <hip/hip_bf16.h>

#define D_MODEL 512
#define BATCH 4
#define SEQ 2048
#define ROWS (BATCH*SEQ)   // 8192

typedef unsigned short u16;
typedef short bf16x8 __attribute__((ext_vector_type(8)));
typedef float f32x4 __attribute__((ext_vector_type(4)));

__device__ __forceinline__ float bf2f(u16 u) {
    union { unsigned int i; float f; } v;
    v.i = ((unsigned int)u) << 16;
    return v.f;
}
__device__ __forceinline__ u16 f2bf(float f) {
    union { float f; unsigned int i; } v;
    v.f = f;
    unsigned int x = v.i;
    unsigned int r = (x >> 16) & 1u;
    x += 0x7fffu + r;           // round-to-nearest-even
    return (u16)(x >> 16);
}

template<int N> __device__ __forceinline__ void waitv() {
    static_assert(N==0 || N==3 || N==4 || N==8, "unsupported vmcnt");
    if constexpr (N == 0) asm volatile("s_waitcnt vmcnt(0)" ::: "memory");
    if constexpr (N == 3) asm volatile("s_waitcnt vmcnt(3)" ::: "memory");
    if constexpr (N == 4) asm volatile("s_waitcnt vmcnt(4)" ::: "memory");
    if constexpr (N == 8) asm volatile("s_waitcnt vmcnt(8)" ::: "memory");
}

// ---------------- fused prep: split x + 4 weights ----------------
__global__ __launch_bounds__(256)
void prep_kernel(const float* __restrict__ x,
                 const float* __restrict__ Wq, const float* __restrict__ Wk,
                 const float* __restrict__ Wv, const float* __restrict__ Wo,
                 u16* __restrict__ xh, u16* __restrict__ xl,
                 u16* __restrict__ whh, u16* __restrict__ whl,
                 u16* __restrict__ woh, u16* __restrict__ wol)
{
    const int blk = blockIdx.x;
    const int tid = threadIdx.x;
    const int WE = 262144;
    const float* src; u16 *dh, *dl; int i;
    if (blk < 4096) {
        src = x; dh = xh; dl = xl;
        i = (blk * 256 + tid) * 4;
    } else {
        int w = (blk - 4096) >> 8;
        src = (w == 0) ? Wq : (w == 1) ? Wk : (w == 2) ? Wv : Wo;
        dh  = (w < 3) ? whh + w * WE : woh;
        dl  = (w < 3) ? whl + w * WE : wol;
        i = (((blk - 4096) & 255) * 256 + tid) * 4;
    }
    float4 v = *(const float4*)(src + i);
    float vv[4] = { v.x, v.y, v.z, v.w };
    u16 hh[4], ll[4];
    #pragma unroll
    for (int j = 0; j < 4; ++j) {
        u16 hi = f2bf(vv[j]);
        hh[j] = hi;
        ll[j] = f2bf(vv[j] - bf2f(hi));
    }
    *(ushort4*)(dh + i) = make_ushort4(hh[0], hh[1], hh[2], hh[3]);
    *(ushort4*)(dl + i) = make_ushort4(ll[0], ll[1], ll[2], ll[3]);
}

// ======== shared GEMM pieces (128^2, 4-wave) ========
#define GEMM_PROLOG                                                            \
    constexpr int BN     = 32 * NF;                                            \
    constexpr int TILE_A = 128 * 32;                                           \
    constexpr int TILE_B = BN * 32;                                            \
    constexpr int ACH    = 8;                                                  \
    constexpr int BCH    = BN / 16;                                            \
    constexpr int NCH    = AT*ACH + BT*BCH;                                    \
    constexpr int CPW    = NCH / 4;                                            \
    constexpr int BUFSZ  = AT*TILE_A + BT*TILE_B;                              \
    const int tid  = threadIdx.x;                                              \
    const int lane = tid & 63;                                                 \
    const int wave = tid >> 6;                                                 \
    const int wr = wave >> 1, wc = wave & 1;                                   \
    const int gx = gridDim.x, gy = gridDim.y;                                  \
    int nwg = gx * gy * gridDim.z;                                             \
    int wg  = blockIdx.x + gx * (blockIdx.y + gy * blockIdx.z);                \
    int id  = (wg & 7) * (nwg >> 3) + (wg >> 3);                               \
    const int bx = id % gx;                                                    \
    const int by = (id / gx) % gy;                                             \
    const int bz = id / (gx * gy);                                             \
    const long aBase = (long)bz * aStride + (long)(bx * 128) * lda;            \
    const long bBase = (long)bz * bStride + (long)(by * BN) * ldb;             \
    const u16* csrc[CPW];                                                      \
    unsigned cdst[CPW];                                                        \
    _Pragma("unroll")                                                          \
    for (int i = 0; i < CPW; ++i) {                                            \
        int c = wave + i * 4;                                                  \
        const u16* sb; int ld, lofs, row;                                      \
        if (c < AT * ACH) {                                                    \
            int t = c >> 3;                                                    \
            row = (c & 7) * 16;                                                \
            sb = (t == 0 ? Ah : Al) + aBase;                                   \
            ld = lda; lofs = t * TILE_A;                                       \
        } else {                                                               \
            int cb = c - AT * ACH;                                             \
            int t = cb / BCH;                                                  \
            row = (cb % BCH) * 16;                                             \
            sb = (t == 0 ? Bh : Bl) + bBase;                                   \
            ld = ldb; lofs = AT * TILE_A + t * TILE_B;                         \
        }                                                                      \
        csrc[i] = sb + (long)(row + (lane >> 2)) * ld + (lane & 3) * 8;        \
        cdst[i] = lofs + row * 32;                                             \
    }                                                                          \
    f32x4 acc[4][NF] = {};                                                     \
    const int frow = lane & 15;                                                \
    const int kofs = (lane >> 4) * 8;

#define GEMM_COMPUTE(bb_)                                                      \
    {                                                                          \
        const int bb = (bb_);                                                  \
        bf16x8 aH[4], aL[4], bH[NF], bL[NF];                                   \
        _Pragma("unroll")                                                      \
        for (int m = 0; m < 4; ++m) {                                          \
            int rA = wr*64 + m*16 + frow;                                      \
            aH[m] = *(const bf16x8*)&lds[bb + rA*32 + kofs];                   \
            if constexpr (AT == 2)                                             \
                aL[m] = *(const bf16x8*)&lds[bb + TILE_A + rA*32 + kofs];      \
        }                                                                      \
        _Pragma("unroll")                                                      \
        for (int n = 0; n < NF; ++n) {                                         \
            int rB = wc*(NF*16) + n*16 + frow;                                 \
            bH[n] = *(const bf16x8*)&lds[bb + AT*TILE_A + rB*32 + kofs];       \
            if constexpr (BT == 2)                                             \
                bL[n] = *(const bf16x8*)&lds[bb + AT*TILE_A + TILE_B + rB*32 + kofs]; \
        }                                                                      \
        _Pragma("unroll")                                                      \
        for (int m = 0; m < 4; ++m)                                            \
            _Pragma("unroll")                                                  \
            for (int n = 0; n < NF; ++n) {                                     \
                acc[m][n] = __builtin_amdgcn_mfma_f32_16x16x32_bf16(aH[m], bH[n], acc[m][n], 0, 0, 0); \
                if constexpr (BT == 2)                                         \
                    acc[m][n] = __builtin_amdgcn_mfma_f32_16x16x32_bf16(aH[m], bL[n], acc[m][n], 0, 0, 0); \
                if constexpr (AT == 2)                                         \
                    acc[m][n] = __builtin_amdgcn_mfma_f32_16x16x32_bf16(aL[m], bH[n], acc[m][n], 0, 0, 0); \
            }                                                                  \
    }

#define GEMM_EPILOG_STAGED                                                     \
    {                                                                          \
    const int rr = (lane >> 4) * 4;                                            \
    __syncthreads();                                                           \
    if (mode == 0) {                                                           \
        float* ldsF = (float*)lds;                                             \
        _Pragma("unroll")                                                      \
        for (int n = 0; n < NF; ++n) {                                         \
            int c = wc*(NF*16) + n*16 + frow;                                  \
            float bv_ = bias ? bias[by*BN + c] : 0.0f;                         \
            _Pragma("unroll")                                                  \
            for (int m = 0; m < 4; ++m)                                        \
                _Pragma("unroll")                                              \
                for (int j = 0; j < 4; ++j)                                    \
                    ldsF[(wr*64 + m*16 + rr + j)*(BN+4) + c] = acc[m][n][j]*scale + bv_; \
        }                                                                      \
        __syncthreads();                                                       \
        for (int idx = tid; idx < 128*(BN/4); idx += 256) {                    \
            int row = idx / (BN/4), c4 = (idx % (BN/4)) * 4;                   \
            *(float4*)&outF[(long)bz*cStride + (long)(bx*128+row)*ldc + by*BN + c4] = \
                *(float4*)&ldsF[row*(BN+4) + c4];                              \
        }                                                                      \
    } else if (mode == 1) {                                                    \
        u16* ldsH = (u16*)lds;                                                 \
        u16* ldsL = (u16*)lds + 128*(BN+12);                                   \
        _Pragma("unroll")                                                      \
        for (int n = 0; n < NF; ++n) {                                         \
            int c = wc*(NF*16) + n*16 + frow;                                  \
            float bv_ = bias ? bias[by*BN + c] : 0.0f;                         \
            _Pragma("unroll")                                                  \
            for (int m = 0; m < 4; ++m)                                        \
                _Pragma("unroll")                                              \
                for (int j = 0; j < 4; ++j) {                                  \
                    int r = wr*64 + m*16 + rr + j;                             \
                    float val = acc[m][n][j]*scale + bv_;                      \
                    u16 h = f2bf(val);                                         \
                    ldsH[r*(BN+12) + c] = h;                                   \
                    if (outL) ldsL[r*(BN+12) + c] = f2bf(val - bf2f(h));       \
                }                                                              \
        }                                                                      \
        __syncthreads();                                                       \
        for (int idx = tid; idx < 128*(BN/8); idx += 256) {                    \
            int row = idx / (BN/8), c8 = (idx % (BN/8)) * 8;                   \
            long o = (long)bz*cStride + (long)(bx*128+row)*ldc + by*BN + c8;   \
            *(bf16x8*)&outH[o] = *(bf16x8*)&ldsH[row*(BN+12) + c8];            \
            if (outL) *(bf16x8*)&outL[o] = *(bf16x8*)&ldsL[row*(BN+12) + c8];  \
        }                                                                      \
    } else {                                                                   \
        u16* ldsT = (u16*)lds;   /* [BN][136]: transposed tile */              \
        _Pragma("unroll")                                                      \
        for (int n = 0; n < NF; ++n) {                                         \
            int c = wc*(NF*16) + n*16 + frow;                                  \
            float bv_ = bias ? bias[by*BN + c] : 0.0f;                         \
            _Pragma("unroll")                                                  \
            for (int m = 0; m < 4; ++m)                                        \
                _Pragma("unroll")                                              \
                for (int j = 0; j < 4; ++j)                                    \
                    ldsT[c*136 + (wr*64 + m*16 + rr + j)] = f2bf(acc[m][n][j]*scale + bv_); \
        }                                                                      \
        __syncthreads();                                                       \
        int b = bx >> 4, mrowBase = (bx & 15) * 128;                           \
        for (int idx = tid; idx < BN*16; idx += 256) {                         \
            int crow = idx >> 4, r8 = (idx & 15) * 8;                          \
            *(bf16x8*)&outH[(long)b*1048576 + (long)(by*BN + crow)*2048 + mrowBase + r8] = \
                *(bf16x8*)&ldsT[crow*136 + r8];                                \
        }                                                                      \
    }                                                                          \
    }

// ---- 2-buffer variant (projections, final) ----
template<int NF, int AT, int BT>
__global__ __launch_bounds__(256)
void gemm2(const u16* __restrict__ Ah, const u16* __restrict__ Al,
           const u16* __restrict__ Bh, const u16* __restrict__ Bl,
           const float* __restrict__ bias,
           float* __restrict__ outF, u16* __restrict__ outH, u16* __restrict__ outL,
           int K, int lda, int ldb, int ldc,
           long aStride, long bStride, long cStride,
           float scale, int mode)
{
    GEMM_PROLOG
    constexpr int EPI1 = 128*(BN+12);
    constexpr int EPI0 = 256*(BN+4);
    constexpr int LDSN = (2*BUFSZ > EPI1 ? (2*BUFSZ > EPI0 ? 2*BUFSZ : EPI0)
                                         : (EPI1 > EPI0 ? EPI1 : EPI0));
    __shared__ u16 lds[LDSN];
    auto stage = [&](int buf, int k0) {
        #pragma unroll
        for (int i = 0; i < CPW; ++i)
            __builtin_amdgcn_global_load_lds(
                (const __attribute__((address_space(1))) unsigned int*)(csrc[i] + k0),
                (__attribute__((address_space(3))) unsigned int*)(&lds[buf * BUFSZ + cdst[i]]),
                16, 0, 0);
    };
    const int nt = K >> 5;
    stage(0, 0);
    __syncthreads();
    int cur = 0;
    for (int t = 0; t < nt; ++t) {
        if (t + 1 < nt) stage(cur ^ 1, (t + 1) << 5);
        GEMM_COMPUTE(cur * BUFSZ)
        __syncthreads();
        cur ^= 1;
    }
    GEMM_EPILOG_STAGED
}

// ---- ring-3 counted-vmcnt variant (PV) ----
template<int NF, int AT, int BT>
__global__ __launch_bounds__(256)
void gemm3(const u16* __restrict__ Ah, const u16* __restrict__ Al,
           const u16* __restrict__ Bh, const u16* __restrict__ Bl,
           const float* __restrict__ bias,
           float* __restrict__ outF, u16* __restrict__ outH, u16* __restrict__ outL,
           int K, int lda, int ldb, int ldc,
           long aStride, long bStride, long cStride,
           float scale, int mode)
{
    GEMM_PROLOG
    constexpr int EPI1 = 256*(BN+12);
    constexpr int LDSN = (3*BUFSZ > EPI1) ? 3*BUFSZ : EPI1;
    __shared__ u16 lds[LDSN];
    auto stage = [&](int buf, int k0) {
        #pragma unroll
        for (int i = 0; i < CPW; ++i)
            __builtin_amdgcn_global_load_lds(
                (const __attribute__((address_space(1))) unsigned int*)(csrc[i] + k0),
                (__attribute__((address_space(3))) unsigned int*)(&lds[buf * BUFSZ + cdst[i]]),
                16, 0, 0);
    };
    const int nt = K >> 5;
    stage(0, 0);
    stage(1, 32);
    for (int t = 0; t < nt; ++t) {
        if (t + 1 < nt) waitv<CPW>();
        else            waitv<0>();
        __builtin_amdgcn_s_barrier();
        __builtin_amdgcn_sched_barrier(0);
        if (t + 2 < nt) stage((t + 2) % 3, (t + 2) << 5);
        GEMM_COMPUTE((t % 3) * BUFSZ)
    }
    GEMM_EPILOG_STAGED
}

// ---- 256x256 tile, 8-wave, BK=64, XOR-swizzled LDS, counted-vmcnt (scores) ----
// T2 (both-sides swizzle: inverse-swizzled global src + swizzled ds_read) +
// T4 (waitv<8> leaves next K-tile's loads in flight; vmcnt(0) only at drain).
__global__ __launch_bounds__(512)
void gemm256p(const u16* __restrict__ A, const u16* __restrict__ B,
              u16* __restrict__ outH,
              int K, int lda, int ldb, int ldc,
              long aStride, long bStride, long cStride, float scale)
{
    // 2 bufs x {A[256][64], B[256][64]} bf16 = 128 KB; epilogue reuses [128][264]
    __shared__ u16 lds[2 * 32768];
    const int tid  = threadIdx.x;
    const int lane = tid & 63;
    const int wave = tid >> 6;              // 0..7
    const int wr = wave >> 2, wc = wave & 3;

    // XCD-aware swizzle (grid %8==0)
    const int gx = gridDim.x, gy = gridDim.y;
    int nwg = gx * gy * gridDim.z;
    int wg  = blockIdx.x + gx * (blockIdx.y + gy * blockIdx.z);
    int id  = (wg & 7) * (nwg >> 3) + (wg >> 3);
    const int bx = id % gx;
    const int by = (id / gx) % gy;
    const int bz = id / (gx * gy);

    const long aBase = (long)bz * aStride + (long)(bx * 256) * lda;
    const long bBase = (long)bz * bStride + (long)(by * 256) * ldb;

    // Staging: 8 gload_lds per thread per K-tile (4 A + 4 B), 64 rows each.
    // LDS row = 64 u16 = 128 B = 8 chunks of 16 B. Swizzle: chunk ^= (row&7).
    // gload_lds writes LINEAR (wave base + lane*16B): lane l -> row rb+l/8,
    // chunk l%8. So the global SOURCE is pre-swizzled: lane loads global
    // chunk (l%8)^((l/8)&7) -> LDS slot (row, l%8) holds global chunk
    // (l%8)^(row&7), matching the swizzled ds_read below (involution).
    const int srow   = lane >> 3;                       // 0..7
    const int schunk = (lane & 7) ^ (srow & 7);         // inverse-swizzled src chunk
    const u16* srcA[4]; const u16* srcB[4];
    unsigned dstA[4], dstB[4];
    #pragma unroll
    for (int i = 0; i < 4; ++i) {
        int rb = i * 64 + wave * 8;                     // wave-uniform row base
        srcA[i] = A + aBase + (long)(rb + srow) * lda + schunk * 8;
        srcB[i] = B + bBase + (long)(rb + srow) * ldb + schunk * 8;
        dstA[i] = rb * 64;
        dstB[i] = 16384 + rb * 64;
    }
    auto stage = [&](int buf, int k0) {
        #pragma unroll
        for (int i = 0; i < 4; ++i)
            __builtin_amdgcn_global_load_lds(
                (const __attribute__((address_space(1))) unsigned int*)(srcA[i] + k0),
                (__attribute__((address_space(3))) unsigned int*)(&lds[buf * 32768 + dstA[i]]),
                16, 0, 0);
        #pragma unroll
        for (int i = 0; i < 4; ++i)
            __builtin_amdgcn_global_load_lds(
                (const __attribute__((address_space(1))) unsigned int*)(srcB[i] + k0),
                (__attribute__((address_space(3))) unsigned int*)(&lds[buf * 32768 + dstB[i]]),
                16, 0, 0);
    };

    f32x4 acc[8][4] = {};
    const int frow = lane & 15;
    const int kq   = lane >> 4;             // 0..3
    const int fswz = frow & 7;

    const int nt = K >> 6;                  // BK=64
    stage(0, 0);
    stage(1, 64);
    for (int t = 0; t < nt; ++t) {
        // drain own stage(t); leave stage(t+1)'s 8 loads in flight
        if (t + 1 < nt) waitv<8>(); else waitv<0>();
        __builtin_amdgcn_s_barrier();           // all waves' stage(t) complete
        __builtin_amdgcn_sched_barrier(0);
        const int bb = (t & 1) * 32768;
        #pragma unroll
        for (int kh = 0; kh < 2; ++kh) {
            const int ch = ((kh << 2) + kq) ^ fswz;     // swizzled chunk 0..7
            bf16x8 aH[8], bH[4];
            #pragma unroll
            for (int m = 0; m < 8; ++m) {
                int rA = wr*128 + m*16 + frow;
                aH[m] = *(const bf16x8*)&lds[bb + rA*64 + ch*8];
            }
            #pragma unroll
            for (int n = 0; n < 4; ++n) {
                int rB = wc*64 + n*16 + frow;
                bH[n] = *(const bf16x8*)&lds[bb + 16384 + rB*64 + ch*8];
            }
            #pragma unroll
            for (int m = 0; m < 8; ++m)
                #pragma unroll
                for (int n = 0; n < 4; ++n)
                    acc[m][n] = __builtin_amdgcn_mfma_f32_16x16x32_bf16(aH[m], bH[n], acc[m][n], 0, 0, 0);
        }
        __builtin_amdgcn_s_barrier();           // all reads of buf[t&1] done
        __builtin_amdgcn_sched_barrier(0);
        if (t + 2 < nt) stage(t & 1, (t + 2) << 6);  // overwrite now safe
    }

    // staged epilogue: two half-tiles through LDS [128][264], coalesced stores
    const int rr = (lane >> 4) * 4;
    #pragma unroll
    for (int h = 0; h < 2; ++h) {
        __syncthreads();
        if (wr == h) {
            #pragma unroll
            for (int n = 0; n < 4; ++n) {
                int c = wc*64 + n*16 + frow;
                #pragma unroll
                for (int m = 0; m < 8; ++m)
                    #pragma unroll
                    for (int j = 0; j < 4; ++j)
                        lds[(m*16 + rr + j)*264 + c] = f2bf(acc[m][n][j] * scale);
            }
        }
        __syncthreads();
        for (int idx = tid; idx < 128*32; idx += 512) {
            int row = idx >> 5, c8 = (idx & 31) * 8;
            *(bf16x8*)&outH[(long)bz*cStride + (long)(bx*256 + h*128 + row)*ldc + by*256 + c8] =
                *(bf16x8*)&lds[row*264 + c8];
        }
    }
}

// ---------------- row softmax over 2048, in-place, bf16 ----------------
__global__ __launch_bounds__(256)
void softmax_kernel(u16* __restrict__ sh)
{
    const long base = (long)blockIdx.x * 2048;
    const int tid = threadIdx.x;
    const int lane = tid & 63, wave = tid >> 6;
    u16* hp = sh + base + tid * 8;
    bf16x8 hv = *(const bf16x8*)hp;
    float s[8];
    #pragma unroll
    for (int j = 0; j < 8; ++j) s[j] = bf2f((u16)hv[j]);

    float mx = s[0];
    #pragma unroll
    for (int j = 1; j < 8; ++j) mx = fmaxf(mx, s[j]);
    #pragma unroll
    for (int off = 32; off >= 1; off >>= 1) mx = fmaxf(mx, __shfl_xor(mx, off));
    __shared__ float red[8];
    if (lane == 0) red[wave] = mx;
    __syncthreads();
    mx = fmaxf(fmaxf(red[0], red[1]), fmaxf(red[2], red[3]));

    float e[8], sum = 0.f;
    #pragma unroll
    for (int j = 0; j < 8; ++j) { e[j] = __expf(s[j] - mx); sum += e[j]; }
    #pragma unroll
    for (int off = 32; off >= 1; off >>= 1) sum += __shfl_xor(sum, off);
    if (lane == 0) red[4 + wave] = sum;
    __syncthreads();
    sum = red[4] + red[5] + red[6] + red[7];
    float inv = 1.0f / sum;

    bf16x8 ho;
    #pragma unroll
    for (int j = 0; j < 8; ++j) ho[j] = (short)f2bf(e[j] * inv);
    *(bf16x8*)hp = ho;
}

extern "C" void kernel_launch(void* const* d_in, const int* in_sizes, int n_in,
                              void* d_out, int out_size, void* d_ws, size_t ws_size,
                              hipStream_t stream)
{
    const float* x  = (const float*)d_in[0];
    const float* Wq = (const float*)d_in[1];
    const float* bq = (const float*)d_in[2];
    const float* Wk = (const float*)d_in[3];
    const float* bk = (const float*)d_in[4];
    const float* Wv = (const float*)d_in[5];
    const float* bv = (const float*)d_in[6];
    const float* Wo = (const float*)d_in[7];
    const float* bo = (const float*)d_in[8];

    char* p = (char*)d_ws;
    auto alloc = [&](size_t bytes) { char* r = p; p += (bytes + 255) & ~(size_t)255; return r; };

    const size_t XE = (size_t)ROWS * D_MODEL;     // 4,194,304
    const size_t WE = (size_t)D_MODEL * D_MODEL;  // 262,144
    const size_t SE = (size_t)BATCH * SEQ * SEQ;  // 16,777,216

    u16* xh   = (u16*)alloc(XE * 2);
    u16* xl   = (u16*)alloc(XE * 2);
    u16* whh  = (u16*)alloc(3 * WE * 2);   // concat Wq,Wk,Wv (hi)
    u16* whl  = (u16*)alloc(3 * WE * 2);   // concat (lo)
    u16* woh  = (u16*)alloc(WE * 2);
    u16* wol  = (u16*)alloc(WE * 2);
    u16* qh   = (u16*)alloc(XE * 2);
    u16* kh   = (u16*)alloc(XE * 2);
    u16* vTh  = (u16*)alloc(XE * 2);
    u16* sh   = (u16*)alloc(SE * 2);
    // att (split) aliases x's split buffers — x dead after V projection
    u16* ath = xh;
    u16* atl = xl;

    // 1. fused prep (1 launch)
    prep_kernel<<<5120, 256, 0, stream>>>(x, Wq, Wk, Wv, Wo,
                                          xh, xl, whh, whl, woh, wol);

    // 2. q/k/v projections: 3-term split, 2-buffer schedule
    gemm2<2,2,2><<<dim3(64, 8, 1), 256, 0, stream>>>(xh, xl, whh, whl, bq,
        nullptr, qh, nullptr, 512, 512, 512, 512, 0, 0, 0, 1.0f, 1);
    gemm2<2,2,2><<<dim3(64, 8, 1), 256, 0, stream>>>(xh, xl, whh + WE, whl + WE, bk,
        nullptr, kh, nullptr, 512, 512, 512, 512, 0, 0, 0, 1.0f, 1);
    gemm2<2,2,2><<<dim3(64, 8, 1), 256, 0, stream>>>(xh, xl, whh + 2*WE, whl + 2*WE, bv,
        nullptr, vTh, nullptr, 512, 512, 512, 512, 0, 0, 0, 1.0f, 2);

    // 3. scores = q@k^T * 1/sqrt(512): 256^2, BK=64, swizzled, counted-vmcnt
    gemm256p<<<dim3(8, 8, 4), 512, 0, stream>>>(qh, kh, sh,
        512, 512, 512, 2048,
        (long)SEQ * 512, (long)SEQ * 512, (long)SEQ * SEQ,
        0.044194173824159216f);

    // 4. softmax rows (bf16 in/out)
    softmax_kernel<<<ROWS, 256, 0, stream>>>(sh);

    // 5. att = p @ v: 1-term, ring-3; split output (feeds 3-term final)
    gemm3<2,1,1><<<dim3(16, 8, 4), 256, 0, stream>>>(sh, nullptr, vTh, nullptr, nullptr,
        nullptr, ath, atl, 2048, 2048, 2048, 512,
        (long)SEQ * SEQ, (long)512 * SEQ, (long)SEQ * 512,
        1.0f, 1);

    // 6. out = att @ Wo^T + bo: 3-term, 2-buffer, fp32 out
    gemm2<2,2,2><<<dim3(64, 8, 1), 256, 0, stream>>>(ath, atl, woh, wol, bo,
        (float*)d_out, nullptr, nullptr, 512, 512, 512, 512,
        0, 0, 0, 1.0f, 0);
}